// Round 5
// baseline (2060.576 us; speedup 1.0000x reference)
//
#include <hip/hip_runtime.h>
#include <hip/hip_bf16.h>

typedef unsigned int  u32;
typedef unsigned short u16;
typedef unsigned long long u64;
typedef __attribute__((ext_vector_type(8))) short bf16x8;
typedef __attribute__((ext_vector_type(4))) float f32x4;

#define B_   1024
#define T_   128
#define NBT  (B_*T_)
#define FBLK 256          // persistent feature blocks (1/CU)
#define FITR 32           // 16-sample groups per block

// ---- ws layout (u16 element offsets) ----
#define WG_OFF   0          // grid_fc [128][2240] bf16
#define WT_OFF   286720     // trunk   [128][192]  bf16
#define WIH_OFF  311296     // W_ih    [512][128]  bf16
#define W2_OFF   376832     // conv2   [32][160]   bf16 (tap-pair, tap9=0)
#define CVT_TOTAL 381952
#define GATES_BYTE_OFF (1u<<20)

__device__ __forceinline__ u16 f2bf(float f){
  u32 u = __float_as_uint(f);
  u32 r = u + 0x7fffu + ((u >> 16) & 1u);   // RNE
  return (u16)(r >> 16);
}
__device__ __forceinline__ float sigm(float x){ return 1.f / (1.f + __expf(-x)); }
__device__ __forceinline__ float tanh_f(float x){ return 2.f / (1.f + __expf(-2.f*x)) - 1.f; }

// LDS-only barrier: waits ds ops, leaves global loads/stores in flight.
__device__ __forceinline__ void bar_lds() {
  __builtin_amdgcn_sched_barrier(0);
  asm volatile("s_waitcnt lgkmcnt(0)" ::: "memory");
  __builtin_amdgcn_s_barrier();
  __builtin_amdgcn_sched_barrier(0);
}

// ---------------------------------------------------------------------------
// K0: weights -> bf16 workspace
// ---------------------------------------------------------------------------
__global__ void k_cvt(const float* __restrict__ gfw, const float* __restrict__ tw,
                      const float* __restrict__ wih, const float* __restrict__ c2w,
                      u16* __restrict__ wsb) {
  int i = blockIdx.x * 256 + threadIdx.x;
  if (i >= CVT_TOTAL) return;
  float v;
  if (i < WT_OFF)        v = gfw[i];
  else if (i < WIH_OFF)  v = tw[i - WT_OFF];
  else if (i < W2_OFF)   v = wih[i - WIH_OFF];
  else {
    int j = i - W2_OFF; int co = j / 160; int k = j - co*160;
    int tap = k >> 4; int ci = k & 15;
    v = (tap < 9) ? c2w[co*144 + ci*9 + tap] : 0.f;
  }
  wsb[i] = f2bf(v);
}

// ---------------------------------------------------------------------------
// K1: PERSISTENT feature pipeline. 256 blocks x 1024 threads (16 waves),
// each block loops FITR=32 groups of 16 samples. All MFMA B operands and
// bias scalars register-resident for the whole kernel.
// ---------------------------------------------------------------------------
__global__ __launch_bounds__(1024, 1) void k_features(
    const float* __restrict__ states,
    const float* __restrict__ c1w, const float* __restrict__ c1b,
    const float* __restrict__ c2b, const float* __restrict__ gfb,
    const float* __restrict__ cfw, const float* __restrict__ cfb,
    const float* __restrict__ tbv, const float* __restrict__ bih,
    const u16* __restrict__ wsb, u16* __restrict__ gates_out)
{
  __shared__ __align__(16) u32 s_u[13824];          // act1 [16][108][16]u16 UNION p_buf [4][16][132]f32 (33.8KB)
  __shared__ __align__(16) u16 s_c2[16][2248];      // 71.9 KB
  __shared__ float s_st[16][96];                    // 6 KB
  __shared__ __align__(16) u16 s_tr[16][200];
  __shared__ __align__(16) u16 s_h0[16][136];
  __shared__ float s_w1[144];
  __shared__ float s_c1b[16];

  u16*   act1  = (u16*)s_u;
  float* p_buf = (float*)s_u;   // [4][16][132]

  const int tid  = threadIdx.x;
  const int lane = tid & 63;
  const int w    = tid >> 6;        // 0..15
  const int arow = lane & 15;
  const int grp  = lane >> 4;

  // ================= persistent register operands =================
  // grid_fc: wave -> (ng = nt-pair, kq = K-quarter)
  const int ng  = w & 3, kq = w >> 2;
  const int ksb = (kq==0)?0:(kq==1)?18:(kq==2)?36:53;
  const int nks = (kq<2)?18:17;
  bf16x8 Bgf[18][2];
  #pragma unroll
  for (int kk = 0; kk < 18; kk++) {
    if (kk < nks) {
      #pragma unroll
      for (int j = 0; j < 2; j++)
        Bgf[kk][j] = *(const bf16x8*)(wsb + WG_OFF +
            (size_t)((ng*2+j)*16 + arow)*2240 + (ksb+kk)*32 + grp*8);
    }
  }
  // W_ih: wave -> 2 gate-tiles
  bf16x8 Bw[2][4];
  #pragma unroll
  for (int jj = 0; jj < 2; jj++)
    #pragma unroll
    for (int ks = 0; ks < 4; ks++)
      Bw[jj][ks] = *(const bf16x8*)(wsb + WIH_OFF +
          (size_t)(((w*2+jj)*16 + arow)*128) + ks*32 + grp*8);
  // trunk: waves 0..7 (load via w&7, unused for w>=8)
  bf16x8 Btr[6];
  #pragma unroll
  for (int ks = 0; ks < 6; ks++)
    Btr[ks] = *(const bf16x8*)(wsb + WT_OFF +
        (size_t)(((w&7)*16 + arow)*192) + ks*32 + grp*8);
  // conv2 tap-pair fragments
  bf16x8 b2f[5][2];
  #pragma unroll
  for (int p = 0; p < 5; p++)
    #pragma unroll
    for (int nt = 0; nt < 2; nt++)
      b2f[p][nt] = *(const bf16x8*)(wsb + W2_OFF + (nt*16 + arow)*160 + p*32 + grp*8);
  // bias scalars
  const float c2b0 = c2b[arow], c2b1 = c2b[16 + arow];
  const float cfbr = cfb[tid & 63];
  const float gfbr = gfb[tid & 127];
  const float tbvr = tbv[(w&7)*16 + arow];
  const float bihr0 = bih[(w*2+0)*16 + arow];
  const float bihr1 = bih[(w*2+1)*16 + arow];

  // ================= pre-loop staging =================
  if (tid < 144) s_w1[tid] = c1w[tid];
  else if (tid < 160) s_c1b[tid-144] = c1b[tid-144];
  for (int i = tid; i < 3456; i += 1024) ((uint4*)s_u)[i] = (uint4){0,0,0,0};
  {
    const int n0 = blockIdx.x * 16;        // iter 0 group
    if (tid < 752) {
      float2 v = *(const float2*)(states + (size_t)n0*94 + tid*2);
      int s = (tid*2)/94, c = (tid*2)%94;
      *(float2*)&s_st[s][c] = v;
    }
  }
  bar_lds();

  const int gh  = grp >> 1;
  const int ci0 = (grp & 1) * 8;

  for (int it = 0; it < FITR; it++) {
    const int n0 = (it*FBLK + blockIdx.x) * 16;

    // -- interval A: conv1 + ctx_fc; issue next states prefetch --
    float2 npre;
    const bool haspre = (it + 1 < FITR) && (tid < 752);
    if (haspre)
      npre = *(const float2*)(states + (size_t)((it+1)*FBLK + blockIdx.x)*16*94 + tid*2);

    for (int i = tid; i < 16*16*70; i += 1024) {
      int s = i / 1120; int r = i - s*1120;
      int ch = r / 70;  int p = r - ch*70;
      int y = p / 10,   x = p - y*10;
      float acc = s_c1b[ch];
      #pragma unroll
      for (int dy = 0; dy < 3; dy++) {
        int yy = y + dy - 1;
        if (yy < 0 || yy >= 7) continue;
        #pragma unroll
        for (int dx = 0; dx < 3; dx++) {
          int xx = x + dx - 1;
          if (xx < 0 || xx >= 10) continue;
          acc = fmaf(s_w1[ch*9 + dy*3 + dx], s_st[s][yy*10 + xx], acc);
        }
      }
      act1[(s*108 + (y+1)*12 + (x+1))*16 + ch] = f2bf(fmaxf(acc, 0.f));
    }
    {
      int s = tid >> 6, o = tid & 63;
      float a = cfbr;
      #pragma unroll
      for (int k = 0; k < 24; k++) a = fmaf(cfw[o*24 + k], s_st[s][70 + k], a);
      s_tr[s][128 + o] = f2bf(fmaxf(a, 0.f));
    }
    bar_lds();   // (1)

    // -- interval B: conv2 MFMA --
    for (int mt = w; mt < 70; mt += 16) {
      int m = mt*16 + arow;
      int s = (int)(((u32)m * 59919u) >> 22); int pos = m - s*70;
      int y = (int)(((u32)pos * 6554u) >> 16); int x = pos - y*10;
      f32x4 acc0 = {0.f,0.f,0.f,0.f}, acc1 = {0.f,0.f,0.f,0.f};
      #pragma unroll
      for (int p = 0; p < 5; p++) {
        int tap = p*2 + gh; if (tap > 8) tap = 8;
        int dy = (tap * 11) >> 5; int dx = tap - dy*3;
        int hp = (y + dy)*12 + (x + dx);
        bf16x8 av = *(const bf16x8*)&act1[(s*108 + hp)*16 + ci0];
        acc0 = __builtin_amdgcn_mfma_f32_16x16x32_bf16(av, b2f[p][0], acc0, 0, 0, 0);
        acc1 = __builtin_amdgcn_mfma_f32_16x16x32_bf16(av, b2f[p][1], acc1, 0, 0, 0);
      }
      #pragma unroll
      for (int r = 0; r < 4; r++) {
        int m2 = mt*16 + grp*4 + r;
        int s2 = (int)(((u32)m2 * 59919u) >> 22); int pos2 = m2 - s2*70;
        s_c2[s2][arow*70 + pos2]        = f2bf(fmaxf(acc0[r] + c2b0, 0.f));
        s_c2[s2][(16 + arow)*70 + pos2] = f2bf(fmaxf(acc1[r] + c2b1, 0.f));
      }
    }
    bar_lds();   // (2)

    // -- interval C: grid_fc MFMA (4 nt-pairs x 4-way K) --
    {
      f32x4 ga0 = {0.f,0.f,0.f,0.f}, ga1 = {0.f,0.f,0.f,0.f};
      #pragma unroll
      for (int kk = 0; kk < 18; kk++) {
        if (kk < nks) {
          int k = (ksb + kk)*32 + grp*8;
          bf16x8 av = *(const bf16x8*)&s_c2[arow][k];
          ga0 = __builtin_amdgcn_mfma_f32_16x16x32_bf16(av, Bgf[kk][0], ga0, 0, 0, 0);
          ga1 = __builtin_amdgcn_mfma_f32_16x16x32_bf16(av, Bgf[kk][1], ga1, 0, 0, 0);
        }
      }
      #pragma unroll
      for (int r = 0; r < 4; r++) {
        int row = kq*16 + grp*4 + r;
        p_buf[row*132 + ng*32 + arow]      = ga0[r];
        p_buf[row*132 + ng*32 + 16 + arow] = ga1[r];
      }
    }
    bar_lds();   // (3)

    // -- interval D: reduce 4 K-quarters + bias + relu --
    {
      int s = tid >> 7, o = tid & 127;
      float a0 = gfbr, a1 = gfbr;
      #pragma unroll
      for (int q = 0; q < 4; q++) {
        a0 += p_buf[(q*16 + s)*132 + o];
        a1 += p_buf[(q*16 + s + 8)*132 + o];
      }
      s_tr[s][o]     = f2bf(fmaxf(a0, 0.f));
      s_tr[s + 8][o] = f2bf(fmaxf(a1, 0.f));
    }
    bar_lds();   // (4)

    // -- interval E: trunk (waves 0-7) | zero act1 for next iter (waves 8-15) --
    if (w < 8) {
      f32x4 tacc = {0.f,0.f,0.f,0.f};
      #pragma unroll
      for (int ks = 0; ks < 6; ks++) {
        int k = ks*32 + grp*8;
        bf16x8 av = *(const bf16x8*)&s_tr[arow][k];
        tacc = __builtin_amdgcn_mfma_f32_16x16x32_bf16(av, Btr[ks], tacc, 0, 0, 0);
      }
      int o = w*16 + arow;
      #pragma unroll
      for (int r = 0; r < 4; r++) {
        int s = grp*4 + r;
        s_h0[s][o] = f2bf(fmaxf(tacc[r] + tbvr, 0.f));
      }
    } else {
      for (int i = tid - 512; i < 3456; i += 512) ((uint4*)s_u)[i] = (uint4){0,0,0,0};
    }
    bar_lds();   // (5)

    // -- interval F: W_ih MFMA -> gates (global); park next states --
    {
      bf16x8 av[4];
      #pragma unroll
      for (int ks = 0; ks < 4; ks++)
        av[ks] = *(const bf16x8*)&s_h0[arow][ks*32 + grp*8];
      #pragma unroll
      for (int jj = 0; jj < 2; jj++) {
        f32x4 hacc = {0.f,0.f,0.f,0.f};
        #pragma unroll
        for (int ks = 0; ks < 4; ks++)
          hacc = __builtin_amdgcn_mfma_f32_16x16x32_bf16(av[ks], Bw[jj][ks], hacc, 0, 0, 0);
        int gate = (w*2 + jj)*16 + arow;
        float bvv = jj ? bihr1 : bihr0;
        #pragma unroll
        for (int r = 0; r < 4; r++) {
          int s = grp*4 + r;
          int n = n0 + s; int tt = n & 127; int bb = n >> 7;
          gates_out[((size_t)tt * B_ + bb) * 512 + gate] = f2bf(hacc[r] + bvv);
        }
      }
    }
    if (haspre) {
      int s = (tid*2)/94, c = (tid*2)%94;
      *(float2*)&s_st[s][c] = npre;
    }
    bar_lds();   // (6) loop end
  }
}

// ---------------------------------------------------------------------------
// K2: MFMA LSTM (unchanged from R4 — known good).
// ---------------------------------------------------------------------------
__global__ __launch_bounds__(512, 1) void k_lstm(
    const u16* __restrict__ gates_x, const float* __restrict__ whh,
    const int* __restrict__ actions,
    const float* __restrict__ aw, const float* __restrict__ ab,
    const float* __restrict__ cw, const float* __restrict__ cb,
    float* __restrict__ out)
{
  __shared__ __align__(16) u16  s_gx[2][16*512];
  __shared__ __align__(16) float s_g[16*524];
  __shared__ __align__(16) u16  s_h[16*136];
  __shared__ int s_act[2048];

  const int tid  = threadIdx.x;
  const int lane = tid & 63;
  const int w    = tid >> 6;
  const int arow = lane & 15;
  const int grp  = lane >> 4;
  const int b0   = blockIdx.x * 16;

  bf16x8 Bv[4][4];
  #pragma unroll
  for (int j = 0; j < 4; j++)
    #pragma unroll
    for (int ks = 0; ks < 4; ks++) {
      const float* src = whh + (size_t)((w*4 + j)*16 + arow)*128 + ks*32 + grp*8;
      float4 x0 = *(const float4*)src;
      float4 x1 = *(const float4*)(src + 4);
      bf16x8 tv;
      tv[0]=(short)f2bf(x0.x); tv[1]=(short)f2bf(x0.y); tv[2]=(short)f2bf(x0.z); tv[3]=(short)f2bf(x0.w);
      tv[4]=(short)f2bf(x1.x); tv[5]=(short)f2bf(x1.y); tv[6]=(short)f2bf(x1.z); tv[7]=(short)f2bf(x1.w);
      Bv[j][ks] = tv;
    }

  for (int i = tid; i < 16*136; i += 512) s_h[i] = 0;
  for (int i = tid; i < 2048; i += 512) s_act[i] = actions[b0*T_ + i];

  const int es  = tid >> 5;
  const int eh0 = (tid & 31) * 4;
  float haw[4][4], hcwv[4];
  #pragma unroll
  for (int j = 0; j < 4; j++)
    #pragma unroll
    for (int c = 0; c < 4; c++) haw[j][c] = aw[j*128 + eh0 + c];
  #pragma unroll
  for (int c = 0; c < 4; c++) hcwv[c] = cw[eh0 + c];
  const float ab0=ab[0], ab1=ab[1], ab2=ab[2], ab3=ab[3], cb0=cb[0];
  float cst[4] = {0.f,0.f,0.f,0.f};

  {
    const u16* src = gates_x + (size_t)b0*512 + tid*16;
    uint4 v0 = *(const uint4*)src;
    uint4 v1 = *(const uint4*)(src + 8);
    *(uint4*)&s_gx[0][tid*16]     = v0;
    *(uint4*)&s_gx[0][tid*16 + 8] = v1;
  }
  __syncthreads();

  for (int t = 0; t < T_; t++) {
    uint4 pre0, pre1;
    const bool haspre = (t + 1 < T_);
    if (haspre) {
      const u16* src = gates_x + ((size_t)(t+1)*B_ + b0)*512 + tid*16;
      pre0 = *(const uint4*)src;
      pre1 = *(const uint4*)(src + 8);
    }

    f32x4 acc[4];
    #pragma unroll
    for (int j = 0; j < 4; j++) acc[j] = (f32x4){0.f,0.f,0.f,0.f};
    #pragma unroll
    for (int ks = 0; ks < 4; ks++) {
      bf16x8 av = *(const bf16x8*)&s_h[arow*136 + ks*32 + grp*8];
      #pragma unroll
      for (int j = 0; j < 4; j++)
        acc[j] = __builtin_amdgcn_mfma_f32_16x16x32_bf16(av, Bv[j][ks], acc[j], 0, 0, 0);
    }
    #pragma unroll
    for (int j = 0; j < 4; j++)
      #pragma unroll
      for (int r = 0; r < 4; r++)
        s_g[(grp*4 + r)*524 + (w*4 + j)*16 + arow] = acc[j][r];

    asm volatile("s_waitcnt lgkmcnt(0)" ::: "memory");
    __builtin_amdgcn_s_barrier();
    __builtin_amdgcn_sched_barrier(0);

    const u16* gx = &s_gx[t & 1][es*512 + eh0];
    u64 gi = *(const u64*)(gx);
    u64 gf = *(const u64*)(gx + 128);
    u64 gg = *(const u64*)(gx + 256);
    u64 go = *(const u64*)(gx + 384);
    float4 si = *(const float4*)&s_g[es*524 + eh0];
    float4 sf = *(const float4*)&s_g[es*524 + eh0 + 128];
    float4 sg = *(const float4*)&s_g[es*524 + eh0 + 256];
    float4 so = *(const float4*)&s_g[es*524 + eh0 + 384];

    float hv[4];
    #pragma unroll
    for (int c = 0; c < 4; c++) {
      float xi = (&si.x)[c] + __uint_as_float((u32)((gi >> (16*c)) & 0xffffu) << 16);
      float xf = (&sf.x)[c] + __uint_as_float((u32)((gf >> (16*c)) & 0xffffu) << 16);
      float xg = (&sg.x)[c] + __uint_as_float((u32)((gg >> (16*c)) & 0xffffu) << 16);
      float xo = (&so.x)[c] + __uint_as_float((u32)((go >> (16*c)) & 0xffffu) << 16);
      float I = sigm(xi), F = sigm(xf), O = sigm(xo), G = tanh_f(xg);
      cst[c] = F*cst[c] + I*G;
      hv[c] = O * tanh_f(cst[c]);
    }
    {
      ushort4 hs;
      hs.x = f2bf(hv[0]); hs.y = f2bf(hv[1]); hs.z = f2bf(hv[2]); hs.w = f2bf(hv[3]);
      *(ushort4*)&s_h[es*136 + eh0] = hs;
    }

    float l0 = hv[0]*haw[0][0] + hv[1]*haw[0][1] + hv[2]*haw[0][2] + hv[3]*haw[0][3];
    float l1 = hv[0]*haw[1][0] + hv[1]*haw[1][1] + hv[2]*haw[1][2] + hv[3]*haw[1][3];
    float l2 = hv[0]*haw[2][0] + hv[1]*haw[2][1] + hv[2]*haw[2][2] + hv[3]*haw[2][3];
    float l3 = hv[0]*haw[3][0] + hv[1]*haw[3][1] + hv[2]*haw[3][2] + hv[3]*haw[3][3];
    float lv = hv[0]*hcwv[0]   + hv[1]*hcwv[1]   + hv[2]*hcwv[2]   + hv[3]*hcwv[3];
    #pragma unroll
    for (int off = 16; off; off >>= 1) {
      l0 += __shfl_xor(l0, off); l1 += __shfl_xor(l1, off);
      l2 += __shfl_xor(l2, off); l3 += __shfl_xor(l3, off);
      lv += __shfl_xor(lv, off);
    }
    if ((tid & 31) == 0) {
      l0 += ab0; l1 += ab1; l2 += ab2; l3 += ab3; lv += cb0;
      float m  = fmaxf(fmaxf(l0, l1), fmaxf(l2, l3));
      float e0 = __expf(l0 - m), e1 = __expf(l1 - m), e2 = __expf(l2 - m), e3 = __expf(l3 - m);
      float S  = e0 + e1 + e2 + e3;
      float lse = __logf(S);
      float p0 = l0 - m - lse, p1 = l1 - m - lse, p2 = l2 - m - lse, p3 = l3 - m - lse;
      int n = (b0 + es) * T_ + t;
      int a = s_act[es*T_ + t];
      float lpa = (a == 0) ? p0 : (a == 1) ? p1 : (a == 2) ? p2 : p3;
      float ent = -(e0*p0 + e1*p1 + e2*p2 + e3*p3) / S;
      out[n]         = lpa;
      out[NBT + n]   = lv;
      out[2*NBT + n] = ent;
    }

    if (haspre) {
      *(uint4*)&s_gx[(t+1) & 1][tid*16]     = pre0;
      *(uint4*)&s_gx[(t+1) & 1][tid*16 + 8] = pre1;
    }
    __syncthreads();
  }
}

extern "C" void kernel_launch(void* const* d_in, const int* in_sizes, int n_in,
                              void* d_out, int out_size, void* d_ws, size_t ws_size,
                              hipStream_t stream) {
  const float* states = (const float*)d_in[0];
  const int*   actions= (const int*)  d_in[1];
  const float* c1w = (const float*)d_in[2];
  const float* c1b = (const float*)d_in[3];
  const float* c2w = (const float*)d_in[4];
  const float* c2b = (const float*)d_in[5];
  const float* gfw = (const float*)d_in[6];
  const float* gfb = (const float*)d_in[7];
  const float* cfw = (const float*)d_in[8];
  const float* cfb = (const float*)d_in[9];
  const float* tw  = (const float*)d_in[10];
  const float* tbv = (const float*)d_in[11];
  const float* wih = (const float*)d_in[12];
  const float* bih = (const float*)d_in[13];
  const float* whh = (const float*)d_in[14];
  const float* aw  = (const float*)d_in[15];
  const float* ab  = (const float*)d_in[16];
  const float* cw  = (const float*)d_in[17];
  const float* cb  = (const float*)d_in[18];
  float* out = (float*)d_out;

  u16* wsb   = (u16*)d_ws;
  u16* gates = (u16*)((char*)d_ws + GATES_BYTE_OFF);

  k_cvt<<<(CVT_TOTAL + 255)/256, 256, 0, stream>>>(gfw, tw, wih, c2w, wsb);
  k_features<<<FBLK, 1024, 0, stream>>>(states, c1w, c1b, c2b, gfb,
                                        cfw, cfb, tbv, bih, wsb, gates);
  k_lstm<<<B_/16, 512, 0, stream>>>(gates, whh, actions, aw, ab, cw, cb, out);
}

// Round 6
// 1419.769 us; speedup vs baseline: 1.4513x; 1.4513x over previous
//
#include <hip/hip_runtime.h>
#include <hip/hip_bf16.h>

typedef unsigned int  u32;
typedef unsigned short u16;
typedef unsigned long long u64;
typedef __attribute__((ext_vector_type(8))) short bf16x8;
typedef __attribute__((ext_vector_type(4))) float f32x4;

#define B_   1024
#define T_   128
#define NBT  (B_*T_)
#define FBLK 256          // persistent feature blocks (1/CU)
#define FITR 32           // 16-sample groups per block

// ---- ws layout (u16 element offsets) ----
#define WG_OFF   0          // grid_fc [128][2240] bf16
#define WT_OFF   286720     // trunk   [128][192]  bf16
#define WIH_OFF  311296     // W_ih    [512][128]  bf16
#define W2_OFF   376832     // conv2   [32][160]   bf16 (tap-pair, tap9=0)
#define W1C_OFF  381952     // conv1   [16][32]    bf16 (taps 0-8 + zeros)
#define CVT_TOTAL 382464
#define GATES_BYTE_OFF (1u<<20)

__device__ __forceinline__ u16 f2bf(float f){
  u32 u = __float_as_uint(f);
  u32 r = u + 0x7fffu + ((u >> 16) & 1u);   // RNE
  return (u16)(r >> 16);
}
__device__ __forceinline__ float sigm(float x){ return 1.f / (1.f + __expf(-x)); }
__device__ __forceinline__ float tanh_f(float x){ return 2.f / (1.f + __expf(-2.f*x)) - 1.f; }

// LDS-only barrier: waits ds ops, leaves global loads/stores in flight.
__device__ __forceinline__ void bar_lds() {
  __builtin_amdgcn_sched_barrier(0);
  asm volatile("s_waitcnt lgkmcnt(0)" ::: "memory");
  __builtin_amdgcn_s_barrier();
  __builtin_amdgcn_sched_barrier(0);
}

// ---------------------------------------------------------------------------
// K0: weights -> bf16 workspace
// ---------------------------------------------------------------------------
__global__ void k_cvt(const float* __restrict__ gfw, const float* __restrict__ tw,
                      const float* __restrict__ wih, const float* __restrict__ c2w,
                      const float* __restrict__ c1w, u16* __restrict__ wsb) {
  int i = blockIdx.x * 256 + threadIdx.x;
  if (i >= CVT_TOTAL) return;
  float v;
  if (i < WT_OFF)        v = gfw[i];
  else if (i < WIH_OFF)  v = tw[i - WT_OFF];
  else if (i < W2_OFF)   v = wih[i - WIH_OFF];
  else if (i < W1C_OFF) {
    int j = i - W2_OFF; int co = j / 160; int k = j - co*160;
    int tap = k >> 4; int ci = k & 15;
    v = (tap < 9) ? c2w[co*144 + ci*9 + tap] : 0.f;
  } else {
    int j = i - W1C_OFF; int ch = j >> 5; int k = j & 31;
    v = (k < 9) ? c1w[ch*9 + k] : 0.f;
  }
  wsb[i] = f2bf(v);
}

// ---------------------------------------------------------------------------
// K1: PERSISTENT feature pipeline. 256 blocks x 1024 threads (16 waves),
// FITR=32 groups of 16 samples. conv1 via im2col+MFMA; T2 swizzle on
// act1 and s_c2; grid_fc B streamed from L2 (no big register arrays).
// ---------------------------------------------------------------------------
__global__ __launch_bounds__(1024, 1) void k_features(
    const float* __restrict__ states,
    const float* __restrict__ c1b,
    const float* __restrict__ c2b, const float* __restrict__ gfb,
    const float* __restrict__ cfw, const float* __restrict__ cfb,
    const float* __restrict__ tbv, const float* __restrict__ bih,
    const u16* __restrict__ wsb, u16* __restrict__ gates_out)
{
  __shared__ __align__(16) u32 s_u[13824];      // 55.3 KB: act1 [16][108][16]u16 ; tail 16.9KB = p_buf [2][16][132]f32
  __shared__ __align__(16) u16 s_c2[16][2304];  // 73.7 KB (row 4608 B ≡ 0 mod 128; swizzled); also im2col patches [1120][24]
  __shared__ float s_st[16][96];                // 6 KB
  __shared__ __align__(16) u16 s_tr[16][200];   // 6.4 KB
  __shared__ __align__(16) u16 s_h0[16][136];   // 4.3 KB

  u16*   act1    = (u16*)s_u;
  float* p_buf   = (float*)((char*)s_u + 38400);   // [2][16][132] f32 (tail of s_u)
  u16*   patches = (u16*)s_c2;                     // [1120][24] u16 (linear, no swizzle)

  const int tid  = threadIdx.x;
  const int lane = tid & 63;
  const int w    = tid >> 6;        // 0..15
  const int arow = lane & 15;
  const int grp  = lane >> 4;       // 0..3

  // ================= small persistent register operands =================
  bf16x8 Bc1 = *(const bf16x8*)(wsb + W1C_OFF + arow*32 + grp*8);   // conv1 chan frag (zeros baked k>=9)
  bf16x8 b2f[5][2];
  #pragma unroll
  for (int p = 0; p < 5; p++)
    #pragma unroll
    for (int nt = 0; nt < 2; nt++)
      b2f[p][nt] = *(const bf16x8*)(wsb + W2_OFF + (nt*16 + arow)*160 + p*32 + grp*8);
  bf16x8 Btr[6];
  #pragma unroll
  for (int ks = 0; ks < 6; ks++)
    Btr[ks] = *(const bf16x8*)(wsb + WT_OFF + (size_t)(((w&7)*16 + arow)*192) + ks*32 + grp*8);
  bf16x8 Bw[2][4];
  #pragma unroll
  for (int jj = 0; jj < 2; jj++)
    #pragma unroll
    for (int ks = 0; ks < 4; ks++)
      Bw[jj][ks] = *(const bf16x8*)(wsb + WIH_OFF + (size_t)(((w*2+jj)*16 + arow)*128) + ks*32 + grp*8);
  // biases / small weights
  float c1bv[4];
  #pragma unroll
  for (int r = 0; r < 4; r++) c1bv[r] = c1b[grp*4 + r];
  const float c2b0 = c2b[arow], c2b1 = c2b[16 + arow];
  const float gfbr = gfb[tid & 127];
  const float tbvr = tbv[(w&7)*16 + arow];
  const float bihr0 = bih[(w*2+0)*16 + arow];
  const float bihr1 = bih[(w*2+1)*16 + arow];
  const int   cfo  = tid & 63;
  const float cfbr = cfb[cfo];
  float cfwr[24];
  #pragma unroll
  for (int k = 0; k < 24; k++) cfwr[k] = cfw[cfo*24 + k];

  // ================= pre-loop staging =================
  for (int i = tid; i < 3456; i += 1024) ((uint4*)s_u)[i] = (uint4){0,0,0,0};  // zero act1 (halo)
  if (tid < 752) {
    float2 v = *(const float2*)(states + (size_t)(blockIdx.x*16)*94 + tid*2);
    int s = (tid*2)/94, c = (tid*2)%94;
    *(float2*)&s_st[s][c] = v;
  }
  bar_lds();

  const int gh  = grp >> 1;
  const int ci0 = (grp & 1) * 8;
  const bf16x8 zv = {0,0,0,0,0,0,0,0};

  for (int it = 0; it < FITR; it++) {
    const int n0 = (it*FBLK + blockIdx.x) * 16;

    // ---- interval A: states prefetch issue; im2col -> patches; ctx_fc ----
    float2 npre;
    const bool haspre = (it + 1 < FITR) && (tid < 752);
    if (haspre)
      npre = *(const float2*)(states + (size_t)((it+1)*FBLK + blockIdx.x)*16*94 + tid*2);

    for (int rr = tid; rr < 1120; rr += 1024) {
      int s = (int)(((u32)rr * 59919u) >> 22); int p = rr - s*70;
      int y = (int)(((u32)p * 6554u) >> 16);   int x = p - y*10;
      const float* gs = &s_st[s][0];
      bf16x8 lo = zv, hi = zv;
      #pragma unroll
      for (int dy = 0; dy < 3; dy++) {
        int yy = y + dy - 1;
        bool yok = (yy >= 0) && (yy < 7);
        #pragma unroll
        for (int dx = 0; dx < 3; dx++) {
          int xx = x + dx - 1;
          bool ok = yok && (xx >= 0) && (xx < 10);
          int idx = ok ? (yy*10 + xx) : 0;
          float val = gs[idx];
          u16 b = f2bf(ok ? val : 0.f);
          int t = dy*3 + dx;
          if (t < 8) lo[t] = (short)b; else hi[t-8] = (short)b;
        }
      }
      *(bf16x8*)&patches[rr*24]     = lo;
      *(bf16x8*)&patches[rr*24 + 8] = hi;
    }
    {
      int s = tid >> 6;                 // = wave id; broadcast reads of s_st
      float a = cfbr;
      #pragma unroll
      for (int k = 0; k < 24; k++) a = fmaf(cfwr[k], s_st[s][70 + k], a);
      s_tr[s][128 + cfo] = f2bf(fmaxf(a, 0.f));
    }
    bar_lds();   // (1)

    // ---- interval B: conv1 MFMA (patches -> act1, swizzled b64 writes) ----
    for (int mt = w; mt < 70; mt += 16) {
      int m = mt*16 + arow;
      int s = (int)(((u32)m * 59919u) >> 22); int pos = m - s*70;
      int y = (int)(((u32)pos * 6554u) >> 16); int x = pos - y*10;
      int hp = (y+1)*12 + (x+1);
      bf16x8 pf = *(const bf16x8*)&patches[m*24 + grp*8];
      pf = (grp < 2) ? pf : zv;
      f32x4 acc = __builtin_amdgcn_mfma_f32_16x16x32_bf16(Bc1, pf, (f32x4){0.f,0.f,0.f,0.f}, 0, 0, 0);
      u16 q0 = f2bf(fmaxf(acc[0] + c1bv[0], 0.f));
      u16 q1 = f2bf(fmaxf(acc[1] + c1bv[1], 0.f));
      u16 q2 = f2bf(fmaxf(acc[2] + c1bv[2], 0.f));
      u16 q3 = f2bf(fmaxf(acc[3] + c1bv[3], 0.f));
      u64 pack = (u64)q0 | ((u64)q1 << 16) | ((u64)q2 << 32) | ((u64)q3 << 48);
      u32 wa = (u32)(((s*108 + hp)*16 + grp*4)*2) ^ (u32)((hp & 7) << 4);
      *(u64*)((char*)act1 + wa) = pack;
    }
    bar_lds();   // (2)

    // ---- interval C: conv2 MFMA (act1 -> s_c2, both swizzled) ----
    for (int mt = w; mt < 70; mt += 16) {
      int m = mt*16 + arow;
      int s = (int)(((u32)m * 59919u) >> 22); int pos = m - s*70;
      int y = (int)(((u32)pos * 6554u) >> 16); int x = pos - y*10;
      f32x4 acc0 = {0.f,0.f,0.f,0.f}, acc1 = {0.f,0.f,0.f,0.f};
      #pragma unroll
      for (int p = 0; p < 5; p++) {
        int tap = p*2 + gh; if (tap > 8) tap = 8;
        int dy = (tap * 11) >> 5; int dx = tap - dy*3;
        int hp = (y + dy)*12 + (x + dx);
        u32 ra = (u32)(((s*108 + hp)*16 + ci0)*2) ^ (u32)((hp & 7) << 4);
        bf16x8 av = *(const bf16x8*)((const char*)act1 + ra);
        acc0 = __builtin_amdgcn_mfma_f32_16x16x32_bf16(av, b2f[p][0], acc0, 0, 0, 0);
        acc1 = __builtin_amdgcn_mfma_f32_16x16x32_bf16(av, b2f[p][1], acc1, 0, 0, 0);
      }
      #pragma unroll
      for (int r = 0; r < 4; r++) {
        int m2 = mt*16 + grp*4 + r;
        int s2 = (int)(((u32)m2 * 59919u) >> 22); int pos2 = m2 - s2*70;
        u32 w0 = (u32)(s2*4608 + (arow*70 + pos2)*2)        ^ (u32)((s2 & 7) << 4);
        u32 w1 = (u32)(s2*4608 + ((16 + arow)*70 + pos2)*2) ^ (u32)((s2 & 7) << 4);
        *(u16*)((char*)s_c2 + w0) = f2bf(fmaxf(acc0[r] + c2b0, 0.f));
        *(u16*)((char*)s_c2 + w1) = f2bf(fmaxf(acc1[r] + c2b1, 0.f));
      }
    }
    bar_lds();   // (3)

    // ---- interval D: grid_fc MFMA (A from swizzled s_c2, B streamed L2) ----
    {
      const int nt = w & 7, kh = w >> 3;
      const int ksb = kh ? 36 : 0, kse = kh ? 70 : 36;
      const u16* bp = wsb + WG_OFF + (size_t)(nt*16 + arow)*2240 + grp*8;
      const u32 abase = (u32)(arow*4608 + grp*16);
      const u32 axor  = (u32)((arow & 7) << 4);
      f32x4 acc0 = {0.f,0.f,0.f,0.f}, acc1 = {0.f,0.f,0.f,0.f};
      for (int ks = ksb; ks < kse; ks += 2) {
        bf16x8 a0 = *(const bf16x8*)((const char*)s_c2 + ((abase + (u32)ks*64) ^ axor));
        bf16x8 b0 = *(const bf16x8*)(bp + (size_t)ks*32);
        bf16x8 a1 = *(const bf16x8*)((const char*)s_c2 + ((abase + (u32)ks*64 + 64) ^ axor));
        bf16x8 b1 = *(const bf16x8*)(bp + (size_t)ks*32 + 32);
        acc0 = __builtin_amdgcn_mfma_f32_16x16x32_bf16(a0, b0, acc0, 0, 0, 0);
        acc1 = __builtin_amdgcn_mfma_f32_16x16x32_bf16(a1, b1, acc1, 0, 0, 0);
      }
      #pragma unroll
      for (int r = 0; r < 4; r++)
        p_buf[(kh*16 + grp*4 + r)*132 + nt*16 + arow] = acc0[r] + acc1[r];
    }
    bar_lds();   // (4)

    // ---- interval E: reduce halves + bias + relu -> s_tr[0..127] ----
    for (int i = tid; i < 2048; i += 1024) {
      int s = i >> 7, o = i & 127;
      float a = p_buf[s*132 + o] + p_buf[(16 + s)*132 + o] + gfbr;
      s_tr[s][o] = f2bf(fmaxf(a, 0.f));
    }
    bar_lds();   // (5)

    // ---- interval F: trunk (waves 0-7) | re-zero act1 tail (waves 8-15) ----
    if (w < 8) {
      f32x4 tacc = {0.f,0.f,0.f,0.f};
      #pragma unroll
      for (int ks = 0; ks < 6; ks++) {
        int k = ks*32 + grp*8;
        bf16x8 av = *(const bf16x8*)&s_tr[arow][k];
        tacc = __builtin_amdgcn_mfma_f32_16x16x32_bf16(av, Btr[ks], tacc, 0, 0, 0);
      }
      int o = w*16 + arow;
      #pragma unroll
      for (int r = 0; r < 4; r++) {
        int s = grp*4 + r;
        s_h0[s][o] = f2bf(fmaxf(tacc[r] + tbvr, 0.f));
      }
    } else {
      // p_buf overlapped act1 bytes [38400,55296): restore zeros (halo region)
      uint4* pz = (uint4*)((char*)s_u + 38400);
      for (int j = tid - 512; j < 1056; j += 512) pz[j] = (uint4){0,0,0,0};
    }
    bar_lds();   // (6)

    // ---- interval G: W_ih MFMA -> gates (global); park next states ----
    {
      bf16x8 av[4];
      #pragma unroll
      for (int ks = 0; ks < 4; ks++)
        av[ks] = *(const bf16x8*)&s_h0[arow][ks*32 + grp*8];
      #pragma unroll
      for (int jj = 0; jj < 2; jj++) {
        f32x4 hacc = {0.f,0.f,0.f,0.f};
        #pragma unroll
        for (int ks = 0; ks < 4; ks++)
          hacc = __builtin_amdgcn_mfma_f32_16x16x32_bf16(av[ks], Bw[jj][ks], hacc, 0, 0, 0);
        int gate = (w*2 + jj)*16 + arow;
        float bvv = jj ? bihr1 : bihr0;
        #pragma unroll
        for (int r = 0; r < 4; r++) {
          int s = grp*4 + r;
          int n = n0 + s; int tt = n & 127; int bb = n >> 7;
          gates_out[((size_t)tt * B_ + bb) * 512 + gate] = f2bf(hacc[r] + bvv);
        }
      }
    }
    if (haspre) {
      int s = (tid*2)/94, c = (tid*2)%94;
      *(float2*)&s_st[s][c] = npre;
    }
    bar_lds();   // (7)
  }
}

// ---------------------------------------------------------------------------
// K2: MFMA LSTM (unchanged — known good).
// ---------------------------------------------------------------------------
__global__ __launch_bounds__(512, 1) void k_lstm(
    const u16* __restrict__ gates_x, const float* __restrict__ whh,
    const int* __restrict__ actions,
    const float* __restrict__ aw, const float* __restrict__ ab,
    const float* __restrict__ cw, const float* __restrict__ cb,
    float* __restrict__ out)
{
  __shared__ __align__(16) u16  s_gx[2][16*512];
  __shared__ __align__(16) float s_g[16*524];
  __shared__ __align__(16) u16  s_h[16*136];
  __shared__ int s_act[2048];

  const int tid  = threadIdx.x;
  const int lane = tid & 63;
  const int w    = tid >> 6;
  const int arow = lane & 15;
  const int grp  = lane >> 4;
  const int b0   = blockIdx.x * 16;

  bf16x8 Bv[4][4];
  #pragma unroll
  for (int j = 0; j < 4; j++)
    #pragma unroll
    for (int ks = 0; ks < 4; ks++) {
      const float* src = whh + (size_t)((w*4 + j)*16 + arow)*128 + ks*32 + grp*8;
      float4 x0 = *(const float4*)src;
      float4 x1 = *(const float4*)(src + 4);
      bf16x8 tv;
      tv[0]=(short)f2bf(x0.x); tv[1]=(short)f2bf(x0.y); tv[2]=(short)f2bf(x0.z); tv[3]=(short)f2bf(x0.w);
      tv[4]=(short)f2bf(x1.x); tv[5]=(short)f2bf(x1.y); tv[6]=(short)f2bf(x1.z); tv[7]=(short)f2bf(x1.w);
      Bv[j][ks] = tv;
    }

  for (int i = tid; i < 16*136; i += 512) s_h[i] = 0;
  for (int i = tid; i < 2048; i += 512) s_act[i] = actions[b0*T_ + i];

  const int es  = tid >> 5;
  const int eh0 = (tid & 31) * 4;
  float haw[4][4], hcwv[4];
  #pragma unroll
  for (int j = 0; j < 4; j++)
    #pragma unroll
    for (int c = 0; c < 4; c++) haw[j][c] = aw[j*128 + eh0 + c];
  #pragma unroll
  for (int c = 0; c < 4; c++) hcwv[c] = cw[eh0 + c];
  const float ab0=ab[0], ab1=ab[1], ab2=ab[2], ab3=ab[3], cb0=cb[0];
  float cst[4] = {0.f,0.f,0.f,0.f};

  {
    const u16* src = gates_x + (size_t)b0*512 + tid*16;
    uint4 v0 = *(const uint4*)src;
    uint4 v1 = *(const uint4*)(src + 8);
    *(uint4*)&s_gx[0][tid*16]     = v0;
    *(uint4*)&s_gx[0][tid*16 + 8] = v1;
  }
  __syncthreads();

  for (int t = 0; t < T_; t++) {
    uint4 pre0, pre1;
    const bool haspre = (t + 1 < T_);
    if (haspre) {
      const u16* src = gates_x + ((size_t)(t+1)*B_ + b0)*512 + tid*16;
      pre0 = *(const uint4*)src;
      pre1 = *(const uint4*)(src + 8);
    }

    f32x4 acc[4];
    #pragma unroll
    for (int j = 0; j < 4; j++) acc[j] = (f32x4){0.f,0.f,0.f,0.f};
    #pragma unroll
    for (int ks = 0; ks < 4; ks++) {
      bf16x8 av = *(const bf16x8*)&s_h[arow*136 + ks*32 + grp*8];
      #pragma unroll
      for (int j = 0; j < 4; j++)
        acc[j] = __builtin_amdgcn_mfma_f32_16x16x32_bf16(av, Bv[j][ks], acc[j], 0, 0, 0);
    }
    #pragma unroll
    for (int j = 0; j < 4; j++)
      #pragma unroll
      for (int r = 0; r < 4; r++)
        s_g[(grp*4 + r)*524 + (w*4 + j)*16 + arow] = acc[j][r];

    asm volatile("s_waitcnt lgkmcnt(0)" ::: "memory");
    __builtin_amdgcn_s_barrier();
    __builtin_amdgcn_sched_barrier(0);

    const u16* gx = &s_gx[t & 1][es*512 + eh0];
    u64 gi = *(const u64*)(gx);
    u64 gf = *(const u64*)(gx + 128);
    u64 gg = *(const u64*)(gx + 256);
    u64 go = *(const u64*)(gx + 384);
    float4 si = *(const float4*)&s_g[es*524 + eh0];
    float4 sf = *(const float4*)&s_g[es*524 + eh0 + 128];
    float4 sg = *(const float4*)&s_g[es*524 + eh0 + 256];
    float4 so = *(const float4*)&s_g[es*524 + eh0 + 384];

    float hv[4];
    #pragma unroll
    for (int c = 0; c < 4; c++) {
      float xi = (&si.x)[c] + __uint_as_float((u32)((gi >> (16*c)) & 0xffffu) << 16);
      float xf = (&sf.x)[c] + __uint_as_float((u32)((gf >> (16*c)) & 0xffffu) << 16);
      float xg = (&sg.x)[c] + __uint_as_float((u32)((gg >> (16*c)) & 0xffffu) << 16);
      float xo = (&so.x)[c] + __uint_as_float((u32)((go >> (16*c)) & 0xffffu) << 16);
      float I = sigm(xi), F = sigm(xf), O = sigm(xo), G = tanh_f(xg);
      cst[c] = F*cst[c] + I*G;
      hv[c] = O * tanh_f(cst[c]);
    }
    {
      ushort4 hs;
      hs.x = f2bf(hv[0]); hs.y = f2bf(hv[1]); hs.z = f2bf(hv[2]); hs.w = f2bf(hv[3]);
      *(ushort4*)&s_h[es*136 + eh0] = hs;
    }

    float l0 = hv[0]*haw[0][0] + hv[1]*haw[0][1] + hv[2]*haw[0][2] + hv[3]*haw[0][3];
    float l1 = hv[0]*haw[1][0] + hv[1]*haw[1][1] + hv[2]*haw[1][2] + hv[3]*haw[1][3];
    float l2 = hv[0]*haw[2][0] + hv[1]*haw[2][1] + hv[2]*haw[2][2] + hv[3]*haw[2][3];
    float l3 = hv[0]*haw[3][0] + hv[1]*haw[3][1] + hv[2]*haw[3][2] + hv[3]*haw[3][3];
    float lv = hv[0]*hcwv[0]   + hv[1]*hcwv[1]   + hv[2]*hcwv[2]   + hv[3]*hcwv[3];
    #pragma unroll
    for (int off = 16; off; off >>= 1) {
      l0 += __shfl_xor(l0, off); l1 += __shfl_xor(l1, off);
      l2 += __shfl_xor(l2, off); l3 += __shfl_xor(l3, off);
      lv += __shfl_xor(lv, off);
    }
    if ((tid & 31) == 0) {
      l0 += ab0; l1 += ab1; l2 += ab2; l3 += ab3; lv += cb0;
      float m  = fmaxf(fmaxf(l0, l1), fmaxf(l2, l3));
      float e0 = __expf(l0 - m), e1 = __expf(l1 - m), e2 = __expf(l2 - m), e3 = __expf(l3 - m);
      float S  = e0 + e1 + e2 + e3;
      float lse = __logf(S);
      float p0 = l0 - m - lse, p1 = l1 - m - lse, p2 = l2 - m - lse, p3 = l3 - m - lse;
      int n = (b0 + es) * T_ + t;
      int a = s_act[es*T_ + t];
      float lpa = (a == 0) ? p0 : (a == 1) ? p1 : (a == 2) ? p2 : p3;
      float ent = -(e0*p0 + e1*p1 + e2*p2 + e3*p3) / S;
      out[n]         = lpa;
      out[NBT + n]   = lv;
      out[2*NBT + n] = ent;
    }

    if (haspre) {
      *(uint4*)&s_gx[(t+1) & 1][tid*16]     = pre0;
      *(uint4*)&s_gx[(t+1) & 1][tid*16 + 8] = pre1;
    }
    __syncthreads();
  }
}

extern "C" void kernel_launch(void* const* d_in, const int* in_sizes, int n_in,
                              void* d_out, int out_size, void* d_ws, size_t ws_size,
                              hipStream_t stream) {
  const float* states = (const float*)d_in[0];
  const int*   actions= (const int*)  d_in[1];
  const float* c1w = (const float*)d_in[2];
  const float* c1b = (const float*)d_in[3];
  const float* c2w = (const float*)d_in[4];
  const float* c2b = (const float*)d_in[5];
  const float* gfw = (const float*)d_in[6];
  const float* gfb = (const float*)d_in[7];
  const float* cfw = (const float*)d_in[8];
  const float* cfb = (const float*)d_in[9];
  const float* tw  = (const float*)d_in[10];
  const float* tbv = (const float*)d_in[11];
  const float* wih = (const float*)d_in[12];
  const float* bih = (const float*)d_in[13];
  const float* whh = (const float*)d_in[14];
  const float* aw  = (const float*)d_in[15];
  const float* ab  = (const float*)d_in[16];
  const float* cw  = (const float*)d_in[17];
  const float* cb  = (const float*)d_in[18];
  float* out = (float*)d_out;

  u16* wsb   = (u16*)d_ws;
  u16* gates = (u16*)((char*)d_ws + GATES_BYTE_OFF);

  k_cvt<<<(CVT_TOTAL + 255)/256, 256, 0, stream>>>(gfw, tw, wih, c2w, c1w, wsb);
  k_features<<<FBLK, 1024, 0, stream>>>(states, c1b, c2b, gfb,
                                        cfw, cfb, tbv, bih, wsb, gates);
  k_lstm<<<B_/16, 512, 0, stream>>>(gates, whh, actions, aw, ab, cw, cb, out);
}

// Round 7
// 1245.715 us; speedup vs baseline: 1.6541x; 1.1397x over previous
//
#include <hip/hip_runtime.h>
#include <hip/hip_bf16.h>

typedef unsigned int  u32;
typedef unsigned short u16;
typedef unsigned long long u64;
typedef __attribute__((ext_vector_type(8))) short bf16x8;
typedef __attribute__((ext_vector_type(4))) float f32x4;

#define B_   1024
#define T_   128
#define NBT  (B_*T_)
#define FBLK 256          // persistent feature blocks (1/CU)
#define FITR 32           // 16-sample groups per block

// ---- ws layout (u16 element offsets) ----
#define WG_OFF   0          // grid_fc [128][2240] bf16, K permuted: k' = pos*32 + ch
#define WT_OFF   286720     // trunk   [128][192]  bf16
#define WIH_OFF  311296     // (unused by kernels now; kept for layout stability)
#define W2_OFF   376832     // conv2   [32][160]   bf16 (tap-pair, tap9=0)
#define W1C_OFF  381952     // conv1   [16][32]    bf16 (taps 0-8 + zeros)
#define CVT_TOTAL 382464
#define TRUNK_BYTE_OFF (1u<<20)   // trunk_ws [T][B][128] bf16 = 33.5 MB

__device__ __forceinline__ u16 f2bf(float f){
  u32 u = __float_as_uint(f);
  u32 r = u + 0x7fffu + ((u >> 16) & 1u);   // RNE
  return (u16)(r >> 16);
}
__device__ __forceinline__ float bf2f(u16 u){ return __uint_as_float((u32)u << 16); }
__device__ __forceinline__ float sigm(float x){ return 1.f / (1.f + __expf(-x)); }
__device__ __forceinline__ float tanh_f(float x){ return 2.f / (1.f + __expf(-2.f*x)) - 1.f; }

// LDS-only barrier: waits ds ops, leaves global loads/stores in flight.
__device__ __forceinline__ void bar_lds() {
  __builtin_amdgcn_sched_barrier(0);
  asm volatile("s_waitcnt lgkmcnt(0)" ::: "memory");
  __builtin_amdgcn_s_barrier();
  __builtin_amdgcn_sched_barrier(0);
}

// ---------------------------------------------------------------------------
// K0: weights -> bf16 workspace. WG columns permuted to k' = pos*32 + ch.
// ---------------------------------------------------------------------------
__global__ void k_cvt(const float* __restrict__ gfw, const float* __restrict__ tw,
                      const float* __restrict__ wih, const float* __restrict__ c2w,
                      const float* __restrict__ c1w, u16* __restrict__ wsb) {
  int i = blockIdx.x * 256 + threadIdx.x;
  if (i >= CVT_TOTAL) return;
  float v;
  if (i < WT_OFF) {
    int o = i / 2240; int k = i - o*2240;
    int pos = k >> 5, ch = k & 31;
    v = gfw[o*2240 + ch*70 + pos];
  }
  else if (i < WIH_OFF)  v = tw[i - WT_OFF];
  else if (i < W2_OFF)   v = wih[i - WIH_OFF];
  else if (i < W1C_OFF) {
    int j = i - W2_OFF; int co = j / 160; int k = j - co*160;
    int tap = k >> 4; int ci = k & 15;
    v = (tap < 9) ? c2w[co*144 + ci*9 + tap] : 0.f;
  } else {
    int j = i - W1C_OFF; int ch = j >> 5; int k = j & 31;
    v = (k < 9) ? c1w[ch*9 + k] : 0.f;
  }
  wsb[i] = f2bf(v);
}

// ---------------------------------------------------------------------------
// K1: PERSISTENT feature pipeline. 256 blocks x 1024 threads (16 waves),
// FITR=32 groups of 16 samples. Outputs TRUNK (bf16) to trunk_ws.
// ---------------------------------------------------------------------------
__global__ __launch_bounds__(1024, 1) void k_features(
    const float* __restrict__ states,
    const float* __restrict__ c1b,
    const float* __restrict__ c2b, const float* __restrict__ gfb,
    const float* __restrict__ cfw, const float* __restrict__ cfb,
    const float* __restrict__ tbv,
    const u16* __restrict__ wsb, u16* __restrict__ trunk_ws)
{
  __shared__ __align__(16) u32 s_u[13824];      // act1 [16][108][16]u16 (55.3KB) UNION p_buf [64][132]f32 (33.8KB)
  __shared__ __align__(16) u16 s_c2[16][2304];  // 73.7 KB swizzled [s][k'=pos*32+ch]; also im2col patches [1120][24]
  __shared__ float s_st[16][96];                // 6 KB
  __shared__ __align__(16) u16 s_tr[16][200];   // 6.4 KB
  __shared__ __align__(16) u16 s_h0[16][136];   // 4.3 KB

  u16*   act1    = (u16*)s_u;
  float* p_buf   = (float*)s_u;                 // [64][132] f32
  u16*   patches = (u16*)s_c2;                  // [1120][24] u16

  const int tid  = threadIdx.x;
  const int lane = tid & 63;
  const int w    = tid >> 6;        // 0..15
  const int arow = lane & 15;
  const int grp  = lane >> 4;       // 0..3

  // ================= small persistent register operands =================
  bf16x8 Bc1 = *(const bf16x8*)(wsb + W1C_OFF + arow*32 + grp*8);   // conv1 A-frag (ch rows)
  bf16x8 b2f[5][2];
  #pragma unroll
  for (int p = 0; p < 5; p++)
    #pragma unroll
    for (int nt = 0; nt < 2; nt++)
      b2f[p][nt] = *(const bf16x8*)(wsb + W2_OFF + (nt*16 + arow)*160 + p*32 + grp*8);
  bf16x8 Btr[6];
  #pragma unroll
  for (int ks = 0; ks < 6; ks++)
    Btr[ks] = *(const bf16x8*)(wsb + WT_OFF + (size_t)(((w&7)*16 + arow)*192) + ks*32 + grp*8);
  // biases
  float c1bv[4], c2bv0[4], c2bv1[4];
  #pragma unroll
  for (int r = 0; r < 4; r++) {
    c1bv[r]  = c1b[grp*4 + r];
    c2bv0[r] = c2b[grp*4 + r];        // tile0 ch = grp*4+r
    c2bv1[r] = c2b[16 + grp*4 + r];   // tile1
  }
  const float gfbr = gfb[tid & 127];
  const float tbvr = tbv[(w&7)*16 + arow];
  const int   cfo  = tid & 63;
  const float cfbr = cfb[cfo];
  float cfwr[24];
  #pragma unroll
  for (int k = 0; k < 24; k++) cfwr[k] = cfw[cfo*24 + k];

  // grid_fc wave partition: ng = col-group (64 cols), kp = K-quarter
  const int ng = w & 3, kp = w >> 2;
  const int ksb = (kp==0)?0:(kp==1)?18:(kp==2)?36:53;
  const int kse = (kp==0)?18:(kp==1)?36:(kp==2)?53:70;

  // ================= pre-loop staging =================
  for (int i = tid; i < 3456; i += 1024) ((uint4*)s_u)[i] = (uint4){0,0,0,0};  // zero full act1
  if (tid < 752) {
    float2 v = *(const float2*)(states + (size_t)(blockIdx.x*16)*94 + tid*2);
    int s = (tid*2)/94, c = (tid*2)%94;
    *(float2*)&s_st[s][c] = v;
  }
  bar_lds();

  const int gh  = grp >> 1;
  const int ci0 = (grp & 1) * 8;
  const bf16x8 zv = {0,0,0,0,0,0,0,0};

  for (int it = 0; it < FITR; it++) {
    const int n0 = (it*FBLK + blockIdx.x) * 16;
    const int t0 = n0 & 127, bb = n0 >> 7;

    // ---- interval A: states prefetch issue; im2col -> patches; ctx_fc ----
    float2 npre;
    const bool haspre = (it + 1 < FITR) && (tid < 752);
    if (haspre)
      npre = *(const float2*)(states + (size_t)((it+1)*FBLK + blockIdx.x)*16*94 + tid*2);

    for (int rr = tid; rr < 1120; rr += 1024) {
      int s = (int)(((u32)rr * 59919u) >> 22); int p = rr - s*70;
      int y = (int)(((u32)p * 6554u) >> 16);   int x = p - y*10;
      const float* gs = &s_st[s][0];
      bf16x8 lo = zv, hi = zv;
      #pragma unroll
      for (int dy = 0; dy < 3; dy++) {
        int yy = y + dy - 1;
        bool yok = (yy >= 0) && (yy < 7);
        #pragma unroll
        for (int dx = 0; dx < 3; dx++) {
          int xx = x + dx - 1;
          bool ok = yok && (xx >= 0) && (xx < 10);
          int idx = ok ? (yy*10 + xx) : 0;
          float val = gs[idx];
          u16 b = f2bf(ok ? val : 0.f);
          int t = dy*3 + dx;
          if (t < 8) lo[t] = (short)b; else hi[t-8] = (short)b;
        }
      }
      *(bf16x8*)&patches[rr*24]     = lo;
      *(bf16x8*)&patches[rr*24 + 8] = hi;
    }
    {
      int s = tid >> 6;                 // wave id -> sample; broadcast s_st reads
      float a = cfbr;
      #pragma unroll
      for (int k = 0; k < 24; k++) a = fmaf(cfwr[k], s_st[s][70 + k], a);
      s_tr[s][128 + cfo] = f2bf(fmaxf(a, 0.f));
    }
    bar_lds();   // (1)

    // ---- interval B: conv1 MFMA (patches -> act1, swizzled b64 writes) ----
    for (int mt = w; mt < 70; mt += 16) {
      int m = mt*16 + arow;
      int s = (int)(((u32)m * 59919u) >> 22); int pos = m - s*70;
      int y = (int)(((u32)pos * 6554u) >> 16); int x = pos - y*10;
      int hp = (y+1)*12 + (x+1);
      bf16x8 pf = *(const bf16x8*)&patches[m*24 + grp*8];
      pf = (grp < 2) ? pf : zv;
      f32x4 acc = __builtin_amdgcn_mfma_f32_16x16x32_bf16(Bc1, pf, (f32x4){0.f,0.f,0.f,0.f}, 0, 0, 0);
      u16 q0 = f2bf(fmaxf(acc[0] + c1bv[0], 0.f));
      u16 q1 = f2bf(fmaxf(acc[1] + c1bv[1], 0.f));
      u16 q2 = f2bf(fmaxf(acc[2] + c1bv[2], 0.f));
      u16 q3 = f2bf(fmaxf(acc[3] + c1bv[3], 0.f));
      u64 pack = (u64)q0 | ((u64)q1 << 16) | ((u64)q2 << 32) | ((u64)q3 << 48);
      u32 wa = (u32)(((s*108 + hp)*16 + grp*4)*2) ^ (u32)((hp & 7) << 4);
      *(u64*)((char*)act1 + wa) = pack;
    }
    bar_lds();   // (2)

    // ---- interval C: conv2 MFMA, SWAPPED operands (W as A, act as B) ----
    // acc[r] = out[ch = nt*16+grp*4+r][m = mt*16+arow] -> b64 write at k'=pos*32+ch
    for (int mt = w; mt < 70; mt += 16) {
      int m = mt*16 + arow;
      int s = (int)(((u32)m * 59919u) >> 22); int pos = m - s*70;
      int y = (int)(((u32)pos * 6554u) >> 16); int x = pos - y*10;
      f32x4 acc0 = {0.f,0.f,0.f,0.f}, acc1 = {0.f,0.f,0.f,0.f};
      #pragma unroll
      for (int p = 0; p < 5; p++) {
        int tap = p*2 + gh; if (tap > 8) tap = 8;
        int dy = (tap * 11) >> 5; int dx = tap - dy*3;
        int hp = (y + dy)*12 + (x + dx);
        u32 ra = (u32)(((s*108 + hp)*16 + ci0)*2) ^ (u32)((hp & 7) << 4);
        bf16x8 bv = *(const bf16x8*)((const char*)act1 + ra);
        acc0 = __builtin_amdgcn_mfma_f32_16x16x32_bf16(b2f[p][0], bv, acc0, 0, 0, 0);
        acc1 = __builtin_amdgcn_mfma_f32_16x16x32_bf16(b2f[p][1], bv, acc1, 0, 0, 0);
      }
      {
        u16 q0 = f2bf(fmaxf(acc0[0] + c2bv0[0], 0.f));
        u16 q1 = f2bf(fmaxf(acc0[1] + c2bv0[1], 0.f));
        u16 q2 = f2bf(fmaxf(acc0[2] + c2bv0[2], 0.f));
        u16 q3 = f2bf(fmaxf(acc0[3] + c2bv0[3], 0.f));
        u64 pk = (u64)q0 | ((u64)q1 << 16) | ((u64)q2 << 32) | ((u64)q3 << 48);
        u32 wa = (u32)(s*4608 + (pos*32 + grp*4)*2) ^ (u32)((s & 7) << 4);
        *(u64*)((char*)s_c2 + wa) = pk;
      }
      {
        u16 q0 = f2bf(fmaxf(acc1[0] + c2bv1[0], 0.f));
        u16 q1 = f2bf(fmaxf(acc1[1] + c2bv1[1], 0.f));
        u16 q2 = f2bf(fmaxf(acc1[2] + c2bv1[2], 0.f));
        u16 q3 = f2bf(fmaxf(acc1[3] + c2bv1[3], 0.f));
        u64 pk = (u64)q0 | ((u64)q1 << 16) | ((u64)q2 << 32) | ((u64)q3 << 48);
        u32 wa = (u32)(s*4608 + (pos*32 + 16 + grp*4)*2) ^ (u32)((s & 7) << 4);
        *(u64*)((char*)s_c2 + wa) = pk;
      }
    }
    bar_lds();   // (3)

    // ---- interval D: grid_fc MFMA, 4 col-groups x 4 K-quarters ----
    {
      const u16* bp0 = wsb + WG_OFF + (size_t)((ng*2+0)*16 + arow)*2240 + grp*8;
      const u16* bp1 = wsb + WG_OFF + (size_t)((ng*2+1)*16 + arow)*2240 + grp*8;
      const u32 abase = (u32)(arow*4608 + grp*16);
      const u32 axor  = (u32)((arow & 7) << 4);
      f32x4 ga0 = {0.f,0.f,0.f,0.f}, ga1 = {0.f,0.f,0.f,0.f};
      for (int ks = ksb; ks < kse; ks++) {
        bf16x8 av = *(const bf16x8*)((const char*)s_c2 + ((abase + (u32)ks*64) ^ axor));
        bf16x8 b0 = *(const bf16x8*)(bp0 + (size_t)ks*32);
        bf16x8 b1 = *(const bf16x8*)(bp1 + (size_t)ks*32);
        ga0 = __builtin_amdgcn_mfma_f32_16x16x32_bf16(av, b0, ga0, 0, 0, 0);
        ga1 = __builtin_amdgcn_mfma_f32_16x16x32_bf16(av, b1, ga1, 0, 0, 0);
      }
      #pragma unroll
      for (int r = 0; r < 4; r++) {
        int row = kp*16 + grp*4 + r;
        p_buf[row*132 + (ng*2+0)*16 + arow] = ga0[r];
        p_buf[row*132 + (ng*2+1)*16 + arow] = ga1[r];
      }
    }
    bar_lds();   // (4)

    // ---- interval E: reduce 4 K-quarters + bias + relu -> s_tr[0..127] ----
    for (int i = tid; i < 2048; i += 1024) {
      int s = i >> 7, o = i & 127;
      float a = gfbr;
      #pragma unroll
      for (int q = 0; q < 4; q++) a += p_buf[(q*16 + s)*132 + o];
      s_tr[s][o] = f2bf(fmaxf(a, 0.f));
    }
    bar_lds();   // (5)

    // ---- interval F: trunk MFMA (waves 0-7) | re-zero p_buf/act1 region ----
    if (w < 8) {
      f32x4 tacc = {0.f,0.f,0.f,0.f};
      #pragma unroll
      for (int ks = 0; ks < 6; ks++) {
        int k = ks*32 + grp*8;
        bf16x8 av = *(const bf16x8*)&s_tr[arow][k];
        tacc = __builtin_amdgcn_mfma_f32_16x16x32_bf16(av, Btr[ks], tacc, 0, 0, 0);
      }
      int o = w*16 + arow;
      #pragma unroll
      for (int r = 0; r < 4; r++) {
        int s = grp*4 + r;
        s_h0[s][o] = f2bf(fmaxf(tacc[r] + tbvr, 0.f));
      }
    } else {
      // restore zeros over p_buf footprint (act1 halo region; interior rewritten next iter)
      for (int j = tid - 512; j < 2112; j += 512) ((uint4*)s_u)[j] = (uint4){0,0,0,0};
    }
    bar_lds();   // (6)

    // ---- interval G: trunk -> global (coalesced); park next states ----
    if (tid < 512) {
      int s = tid >> 5, o0 = (tid & 31) * 4;
      ushort4 hq = *(const ushort4*)&s_h0[s][o0];
      *(ushort4*)(trunk_ws + ((size_t)(t0 + s)*B_ + bb)*128 + o0) = hq;
    }
    if (haspre) {
      int s = (tid*2)/94, c = (tid*2)%94;
      *(float2*)&s_st[s][c] = npre;
    }
    bar_lds();   // (7)
  }
}

// ---------------------------------------------------------------------------
// K2: fused LSTM. 64 blocks x 16 batch rows x 512 threads (8 waves).
// Computes x-gates from trunk one step ahead (in-register), recurrence MFMA,
// fully in-register cell update (lane owns i,f,g,o of one h for 4 samples),
// heads for t-1 overlapped into phase 1. 2 barriers/step.
// ---------------------------------------------------------------------------
__global__ __launch_bounds__(512, 1) void k_lstm(
    const u16* __restrict__ trunk_ws, const float* __restrict__ whh,
    const float* __restrict__ wih, const float* __restrict__ bih,
    const int* __restrict__ actions,
    const float* __restrict__ aw, const float* __restrict__ ab,
    const float* __restrict__ cw, const float* __restrict__ cb,
    float* __restrict__ out)
{
  __shared__ __align__(16) u16 s_tk[2][16*136];   // trunk tiles, double-buffered
  __shared__ __align__(16) u16 s_h[16*136];       // h bf16 [sample][128]
  __shared__ int s_act[2048];

  const int tid  = threadIdx.x;
  const int lane = tid & 63;
  const int w    = tid >> 6;        // 0..7
  const int arow = lane & 15;
  const int grp  = lane >> 4;
  const int b0   = blockIdx.x * 16;

  // B fragments, rows j*128 + w*16 + arow  (j = gate type i,f,g,o)
  bf16x8 Bv[4][4], Bw[4][4];
  float bihv[4];
  #pragma unroll
  for (int j = 0; j < 4; j++) {
    const int row = j*128 + w*16 + arow;
    bihv[j] = bih[row];
    #pragma unroll
    for (int ks = 0; ks < 4; ks++) {
      const float* s1 = whh + (size_t)row*128 + ks*32 + grp*8;
      const float* s2 = wih + (size_t)row*128 + ks*32 + grp*8;
      float4 a0 = *(const float4*)s1, a1 = *(const float4*)(s1 + 4);
      float4 b0v = *(const float4*)s2, b1v = *(const float4*)(s2 + 4);
      bf16x8 t1, t2;
      t1[0]=(short)f2bf(a0.x); t1[1]=(short)f2bf(a0.y); t1[2]=(short)f2bf(a0.z); t1[3]=(short)f2bf(a0.w);
      t1[4]=(short)f2bf(a1.x); t1[5]=(short)f2bf(a1.y); t1[6]=(short)f2bf(a1.z); t1[7]=(short)f2bf(a1.w);
      t2[0]=(short)f2bf(b0v.x); t2[1]=(short)f2bf(b0v.y); t2[2]=(short)f2bf(b0v.z); t2[3]=(short)f2bf(b0v.w);
      t2[4]=(short)f2bf(b1v.x); t2[5]=(short)f2bf(b1v.y); t2[6]=(short)f2bf(b1v.z); t2[7]=(short)f2bf(b1v.w);
      Bv[j][ks] = t1; Bw[j][ks] = t2;
    }
  }

  for (int i = tid; i < 16*136; i += 512) s_h[i] = 0;
  for (int i = tid; i < 2048; i += 512) s_act[i] = actions[b0*T_ + i];

  // heads lane mapping
  const int es  = tid >> 5;          // sample 0..15
  const int eh0 = (tid & 31) * 4;    // 4 h-cells
  float haw[4][4], hcwv[4];
  #pragma unroll
  for (int j = 0; j < 4; j++)
    #pragma unroll
    for (int c = 0; c < 4; c++) haw[j][c] = aw[j*128 + eh0 + c];
  #pragma unroll
  for (int c = 0; c < 4; c++) hcwv[c] = cw[eh0 + c];
  const float ab0=ab[0], ab1=ab[1], ab2=ab[2], ab3=ab[3], cb0=cb[0];
  float cst[4] = {0.f,0.f,0.f,0.f};

  // stage trunk tiles t=0,1
  if (tid < 256) {
    int row = tid >> 4, c0 = (tid & 15) * 8;
    *(uint4*)&s_tk[0][row*136 + c0] = *(const uint4*)(trunk_ws + ((size_t)0*B_ + b0 + row)*128 + c0);
    *(uint4*)&s_tk[1][row*136 + c0] = *(const uint4*)(trunk_ws + ((size_t)1*B_ + b0 + row)*128 + c0);
  }
  __syncthreads();

  // xA = X(0)
  f32x4 xA[4];
  #pragma unroll
  for (int j = 0; j < 4; j++) xA[j] = (f32x4){0.f,0.f,0.f,0.f};
  #pragma unroll
  for (int ks = 0; ks < 4; ks++) {
    bf16x8 av = *(const bf16x8*)&s_tk[0][arow*136 + ks*32 + grp*8];
    #pragma unroll
    for (int j = 0; j < 4; j++)
      xA[j] = __builtin_amdgcn_mfma_f32_16x16x32_bf16(av, Bw[j][ks], xA[j], 0, 0, 0);
  }

#define HEADS(TT) do {                                                          \
    ushort4 hq = *(const ushort4*)&s_h[es*136 + eh0];                           \
    float h0f=bf2f(hq.x), h1f=bf2f(hq.y), h2f=bf2f(hq.z), h3f=bf2f(hq.w);       \
    float l0 = h0f*haw[0][0] + h1f*haw[0][1] + h2f*haw[0][2] + h3f*haw[0][3];   \
    float l1 = h0f*haw[1][0] + h1f*haw[1][1] + h2f*haw[1][2] + h3f*haw[1][3];   \
    float l2 = h0f*haw[2][0] + h1f*haw[2][1] + h2f*haw[2][2] + h3f*haw[2][3];   \
    float l3 = h0f*haw[3][0] + h1f*haw[3][1] + h2f*haw[3][2] + h3f*haw[3][3];   \
    float lv = h0f*hcwv[0]   + h1f*hcwv[1]   + h2f*hcwv[2]   + h3f*hcwv[3];     \
    _Pragma("unroll")                                                           \
    for (int off = 16; off; off >>= 1) {                                        \
      l0 += __shfl_xor(l0, off); l1 += __shfl_xor(l1, off);                     \
      l2 += __shfl_xor(l2, off); l3 += __shfl_xor(l3, off);                     \
      lv += __shfl_xor(lv, off);                                                \
    }                                                                           \
    if ((tid & 31) == 0) {                                                      \
      float L0 = l0 + ab0, L1 = l1 + ab1, L2 = l2 + ab2, L3 = l3 + ab3;         \
      float Lv = lv + cb0;                                                      \
      float mm = fmaxf(fmaxf(L0, L1), fmaxf(L2, L3));                           \
      float e0 = __expf(L0-mm), e1 = __expf(L1-mm), e2 = __expf(L2-mm), e3 = __expf(L3-mm); \
      float S = e0+e1+e2+e3; float lse = __logf(S);                             \
      float p0=L0-mm-lse, p1=L1-mm-lse, p2=L2-mm-lse, p3=L3-mm-lse;             \
      int n = (b0 + es) * T_ + (TT);                                            \
      int a = s_act[es*T_ + (TT)];                                              \
      float lpa = (a==0)?p0:(a==1)?p1:(a==2)?p2:p3;                             \
      float ent = -(e0*p0 + e1*p1 + e2*p2 + e3*p3) / S;                         \
      out[n] = lpa; out[NBT + n] = Lv; out[2*NBT + n] = ent;                    \
    }                                                                           \
  } while (0)

  for (int t = 0; t < T_; t++) {
    // ---- phase 1: prefetch trunk[t+2]; heads(t-1); racc; xB = X(t+1) ----
    uint4 pre;
    const bool haspre = (t + 2 < T_) && (tid < 256);
    if (haspre)
      pre = *(const uint4*)(trunk_ws + ((size_t)(t+2)*B_ + b0 + (tid>>4))*128 + (tid&15)*8);

    if (t > 0) { HEADS(t-1); }

    f32x4 racc[4], xB[4];
    #pragma unroll
    for (int j = 0; j < 4; j++) { racc[j] = (f32x4){0.f,0.f,0.f,0.f}; xB[j] = (f32x4){0.f,0.f,0.f,0.f}; }
    #pragma unroll
    for (int ks = 0; ks < 4; ks++) {
      bf16x8 av = *(const bf16x8*)&s_h[arow*136 + ks*32 + grp*8];
      #pragma unroll
      for (int j = 0; j < 4; j++)
        racc[j] = __builtin_amdgcn_mfma_f32_16x16x32_bf16(av, Bv[j][ks], racc[j], 0, 0, 0);
    }
    {
      const u16* tk = &s_tk[(t+1)&1][0];
      #pragma unroll
      for (int ks = 0; ks < 4; ks++) {
        bf16x8 av = *(const bf16x8*)&tk[arow*136 + ks*32 + grp*8];
        #pragma unroll
        for (int j = 0; j < 4; j++)
          xB[j] = __builtin_amdgcn_mfma_f32_16x16x32_bf16(av, Bw[j][ks], xB[j], 0, 0, 0);
      }
    }
    bar_lds();   // barA: all s_h / s_tk reads complete

    // ---- phase 2: cell update (in-register), h write, park trunk[t+2] ----
    #pragma unroll
    for (int r = 0; r < 4; r++) {
      float xi = racc[0][r] + xA[0][r] + bihv[0];
      float xf = racc[1][r] + xA[1][r] + bihv[1];
      float xg = racc[2][r] + xA[2][r] + bihv[2];
      float xo = racc[3][r] + xA[3][r] + bihv[3];
      float I = sigm(xi), F = sigm(xf), O = sigm(xo), G = tanh_f(xg);
      cst[r] = F*cst[r] + I*G;
      float hvv = O * tanh_f(cst[r]);
      s_h[(grp*4 + r)*136 + w*16 + arow] = f2bf(hvv);
    }
    if (haspre)
      *(uint4*)&s_tk[t & 1][(tid>>4)*136 + (tid&15)*8] = pre;
    #pragma unroll
    for (int j = 0; j < 4; j++) xA[j] = xB[j];
    bar_lds();   // barB: h(t) visible
  }
  HEADS(T_ - 1);
#undef HEADS
}

extern "C" void kernel_launch(void* const* d_in, const int* in_sizes, int n_in,
                              void* d_out, int out_size, void* d_ws, size_t ws_size,
                              hipStream_t stream) {
  const float* states = (const float*)d_in[0];
  const int*   actions= (const int*)  d_in[1];
  const float* c1w = (const float*)d_in[2];
  const float* c1b = (const float*)d_in[3];
  const float* c2w = (const float*)d_in[4];
  const float* c2b = (const float*)d_in[5];
  const float* gfw = (const float*)d_in[6];
  const float* gfb = (const float*)d_in[7];
  const float* cfw = (const float*)d_in[8];
  const float* cfb = (const float*)d_in[9];
  const float* tw  = (const float*)d_in[10];
  const float* tbv = (const float*)d_in[11];
  const float* wih = (const float*)d_in[12];
  const float* bih = (const float*)d_in[13];
  const float* whh = (const float*)d_in[14];
  const float* aw  = (const float*)d_in[15];
  const float* ab  = (const float*)d_in[16];
  const float* cw  = (const float*)d_in[17];
  const float* cb  = (const float*)d_in[18];
  float* out = (float*)d_out;

  u16* wsb   = (u16*)d_ws;
  u16* trunk = (u16*)((char*)d_ws + TRUNK_BYTE_OFF);

  k_cvt<<<(CVT_TOTAL + 255)/256, 256, 0, stream>>>(gfw, tw, wih, c2w, c1w, wsb);
  k_features<<<FBLK, 1024, 0, stream>>>(states, c1b, c2b, gfb,
                                        cfw, cfb, tbv, wsb, trunk);
  k_lstm<<<B_/16, 512, 0, stream>>>(trunk, whh, wih, bih, actions,
                                    aw, ab, cw, cb, out);
}

// Round 8
// 1236.969 us; speedup vs baseline: 1.6658x; 1.0071x over previous
//
#include <hip/hip_runtime.h>
#include <hip/hip_bf16.h>

typedef unsigned int  u32;
typedef unsigned short u16;
typedef unsigned long long u64;
typedef __attribute__((ext_vector_type(8))) short bf16x8;
typedef __attribute__((ext_vector_type(4))) float f32x4;

#define B_   1024
#define T_   128
#define NBT  (B_*T_)
#define FBLK 256
#define FITR 32

// ---- ws layout (u16 element offsets) ----
#define WG_OFF   0          // grid_fc [128][2240] bf16, K permuted: k' = pos*32 + ch
#define WT_OFF   286720     // trunk   [128][192]  bf16
#define WIH_OFF  311296     // (unused; layout stability)
#define W2_OFF   376832     // conv2   [32][160]   bf16 (tap-pair, tap9=0)
#define W1C_OFF  381952     // conv1   [16][32]    bf16 (taps 0-8 + zeros)
#define CVT_TOTAL 382464
#define TRUNK_BYTE_OFF (1ull<<20)    // trunk_ws [T][B][128] bf16 = 33.5 MB
#define H_BYTE_OFF     (40ull<<20)   // h_ws     [T][B][128] bf16 = 33.5 MB

__device__ __forceinline__ u16 f2bf(float f){
  u32 u = __float_as_uint(f);
  u32 r = u + 0x7fffu + ((u >> 16) & 1u);   // RNE
  return (u16)(r >> 16);
}
__device__ __forceinline__ float bf2f(u16 u){ return __uint_as_float((u32)u << 16); }
__device__ __forceinline__ float sigm(float x){ return 1.f / (1.f + __expf(-x)); }
__device__ __forceinline__ float tanh_f(float x){ return 2.f / (1.f + __expf(-2.f*x)) - 1.f; }

__device__ __forceinline__ void bar_lds() {
  __builtin_amdgcn_sched_barrier(0);
  asm volatile("s_waitcnt lgkmcnt(0)" ::: "memory");
  __builtin_amdgcn_s_barrier();
  __builtin_amdgcn_sched_barrier(0);
}
__device__ __forceinline__ void wave_lds_fence() {
  __builtin_amdgcn_sched_barrier(0);
  asm volatile("s_waitcnt lgkmcnt(0)" ::: "memory");
  __builtin_amdgcn_sched_barrier(0);
}

// ---------------------------------------------------------------------------
// K0: weights -> bf16 workspace. WG columns permuted to k' = pos*32 + ch.
// ---------------------------------------------------------------------------
__global__ void k_cvt(const float* __restrict__ gfw, const float* __restrict__ tw,
                      const float* __restrict__ wih, const float* __restrict__ c2w,
                      const float* __restrict__ c1w, u16* __restrict__ wsb) {
  int i = blockIdx.x * 256 + threadIdx.x;
  if (i >= CVT_TOTAL) return;
  float v;
  if (i < WT_OFF) {
    int o = i / 2240; int k = i - o*2240;
    int pos = k >> 5, ch = k & 31;
    v = gfw[o*2240 + ch*70 + pos];
  }
  else if (i < WIH_OFF)  v = tw[i - WT_OFF];
  else if (i < W2_OFF)   v = wih[i - WIH_OFF];
  else if (i < W1C_OFF) {
    int j = i - W2_OFF; int co = j / 160; int k = j - co*160;
    int tap = k >> 4; int ci = k & 15;
    v = (tap < 9) ? c2w[co*144 + ci*9 + tap] : 0.f;
  } else {
    int j = i - W1C_OFF; int ch = j >> 5; int k = j & 31;
    v = (k < 9) ? c1w[ch*9 + k] : 0.f;
  }
  wsb[i] = f2bf(v);
}

// ---------------------------------------------------------------------------
// K1: PERSISTENT feature pipeline. 256 blocks x 1024 threads (16 waves).
// Wave w owns sample w end-to-end through the conv pipeline (no barriers
// inside: per-wave LDS ops are in-order; lgkmcnt fences between stages).
// 4 barriers/iter: [convs] b1 [grid_fc] b2 [reduce] b3 [trunk/store/zero] b4.
// ---------------------------------------------------------------------------
__global__ __launch_bounds__(1024, 1) void k_features(
    const float* __restrict__ states,
    const float* __restrict__ c1b,
    const float* __restrict__ c2b, const float* __restrict__ gfb,
    const float* __restrict__ cfw, const float* __restrict__ cfb,
    const float* __restrict__ tbv,
    const u16* __restrict__ wsb, u16* __restrict__ trunk_ws)
{
  __shared__ __align__(16) u32 s_u[13824];      // act1 [16][108][16]u16 (55.3KB) UNION p_buf [64][132]f32 (33.8KB)
  __shared__ __align__(16) u16 s_c2[16][2304];  // 73.7KB swizzled [s][k'=pos*32+ch]; row w also holds patches[80][24]
  __shared__ float s_st[16][96];                // 6 KB
  __shared__ __align__(16) u16 s_tr[16][200];   // 6.4 KB
  __shared__ float s_cf[64][25];                // 6.4 KB ctx weights (padded rows)

  u16*   act1  = (u16*)s_u;
  float* p_buf = (float*)s_u;                   // [64][132] f32

  const int tid  = threadIdx.x;
  const int lane = tid & 63;
  const int w    = tid >> 6;        // 0..15 = sample id
  const int arow = lane & 15;
  const int grp  = lane >> 4;       // 0..3

  // ---- small persistent register operands ----
  bf16x8 Bc1 = *(const bf16x8*)(wsb + W1C_OFF + arow*32 + grp*8);
  bf16x8 b2f[5][2];
  #pragma unroll
  for (int p = 0; p < 5; p++)
    #pragma unroll
    for (int nt = 0; nt < 2; nt++)
      b2f[p][nt] = *(const bf16x8*)(wsb + W2_OFF + (nt*16 + arow)*160 + p*32 + grp*8);
  bf16x8 Btr[6];
  #pragma unroll
  for (int ks = 0; ks < 6; ks++)
    Btr[ks] = *(const bf16x8*)(wsb + WT_OFF + (size_t)(((w&7)*16 + arow)*192) + ks*32 + grp*8);
  float c1bv[4], c2bv0[4], c2bv1[4];
  #pragma unroll
  for (int r = 0; r < 4; r++) {
    c1bv[r]  = c1b[grp*4 + r];
    c2bv0[r] = c2b[grp*4 + r];
    c2bv1[r] = c2b[16 + grp*4 + r];
  }
  const float gfbr = gfb[tid & 127];
  const float tbvr = tbv[(w&7)*16 + arow];
  const float cfbr = cfb[lane];

  // grid_fc wave partition
  const int ng = w & 3, kp = w >> 2;
  const int ksb = (kp==0)?0:(kp==1)?18:(kp==2)?36:53;
  const int kse = (kp==0)?18:(kp==1)?36:(kp==2)?53:70;

  // ---- pre-loop staging ----
  for (int i = tid; i < 3456; i += 1024) ((uint4*)s_u)[i] = (uint4){0,0,0,0};  // zero full act1
  if (tid < 752) {
    float2 v = *(const float2*)(states + (size_t)(blockIdx.x*16)*94 + tid*2);
    int s = (tid*2)/94, c = (tid*2)%94;
    *(float2*)&s_st[s][c] = v;
  }
  for (int i = tid; i < 64*24; i += 1024) s_cf[i/24][i%24] = cfw[i];
  bar_lds();

  const int gh  = grp >> 1;
  const int ci0 = (grp & 1) * 8;
  const bf16x8 zv = {0,0,0,0,0,0,0,0};
  u16* patches_w = &s_c2[w][0];                 // [80][24] u16, row w only

  for (int it = 0; it < FITR; it++) {
    const int n0 = (it*FBLK + blockIdx.x) * 16;
    const int t0 = n0 & 127, bb = n0 >> 7;

    // ==== P1: per-wave sample pipeline (no barriers inside) ====
    float2 npre;
    const bool haspre = (it + 1 < FITR) && (tid < 752);
    if (haspre)
      npre = *(const float2*)(states + (size_t)((it+1)*FBLK + blockIdx.x)*16*94 + tid*2);

    // im2col of sample w -> patches_w
    for (int pp = lane; pp < 70; pp += 64) {
      int y = (int)(((u32)pp * 6554u) >> 16); int x = pp - y*10;
      const float* gs = &s_st[w][0];
      bf16x8 lo = zv, hi = zv;
      #pragma unroll
      for (int dy = 0; dy < 3; dy++) {
        int yy = y + dy - 1;
        bool yok = (yy >= 0) && (yy < 7);
        #pragma unroll
        for (int dx = 0; dx < 3; dx++) {
          int xx = x + dx - 1;
          bool ok = yok && (xx >= 0) && (xx < 10);
          int idx = ok ? (yy*10 + xx) : 0;
          float val = gs[idx];
          u16 b = f2bf(ok ? val : 0.f);
          int t = dy*3 + dx;
          if (t < 8) lo[t] = (short)b; else hi[t-8] = (short)b;
        }
      }
      *(bf16x8*)&patches_w[pp*24]     = lo;
      *(bf16x8*)&patches_w[pp*24 + 8] = hi;
    }
    // ctx_fc for sample w (broadcast s_st reads)
    {
      float a = cfbr;
      #pragma unroll
      for (int k = 0; k < 24; k++) a = fmaf(s_cf[lane][k], s_st[w][70 + k], a);
      s_tr[w][128 + lane] = f2bf(fmaxf(a, 0.f));
    }
    wave_lds_fence();

    // conv1 MFMA: 5 pos-tiles of sample w
    #pragma unroll
    for (int tile = 0; tile < 5; tile++) {
      int pos  = tile*16 + arow;
      int posc = (pos < 70) ? pos : 69;
      bf16x8 pf = (grp < 2) ? *(const bf16x8*)&patches_w[posc*24 + grp*8] : zv;
      f32x4 acc = __builtin_amdgcn_mfma_f32_16x16x32_bf16(Bc1, pf, (f32x4){0.f,0.f,0.f,0.f}, 0, 0, 0);
      int y = (int)(((u32)posc * 6554u) >> 16); int x = posc - y*10;
      int hp = (y+1)*12 + (x+1);
      if (pos < 70) {
        u16 q0 = f2bf(fmaxf(acc[0] + c1bv[0], 0.f));
        u16 q1 = f2bf(fmaxf(acc[1] + c1bv[1], 0.f));
        u16 q2 = f2bf(fmaxf(acc[2] + c1bv[2], 0.f));
        u16 q3 = f2bf(fmaxf(acc[3] + c1bv[3], 0.f));
        u64 pk = (u64)q0 | ((u64)q1 << 16) | ((u64)q2 << 32) | ((u64)q3 << 48);
        u32 wa = (u32)(((w*108 + hp)*16 + grp*4)*2) ^ (u32)((hp & 7) << 4);
        *(u64*)((char*)act1 + wa) = pk;
      }
    }
    wave_lds_fence();

    // conv2 MFMA (swapped operands): 5 pos-tiles of sample w -> s_c2 row w
    #pragma unroll
    for (int tile = 0; tile < 5; tile++) {
      int pos  = tile*16 + arow;
      int posc = (pos < 70) ? pos : 69;
      int y = (int)(((u32)posc * 6554u) >> 16); int x = posc - y*10;
      f32x4 acc0 = {0.f,0.f,0.f,0.f}, acc1 = {0.f,0.f,0.f,0.f};
      #pragma unroll
      for (int p = 0; p < 5; p++) {
        int tap = p*2 + gh; if (tap > 8) tap = 8;
        int dy = (tap * 11) >> 5; int dx = tap - dy*3;
        int hp = (y + dy)*12 + (x + dx);
        u32 ra = (u32)(((w*108 + hp)*16 + ci0)*2) ^ (u32)((hp & 7) << 4);
        bf16x8 bv = *(const bf16x8*)((const char*)act1 + ra);
        acc0 = __builtin_amdgcn_mfma_f32_16x16x32_bf16(b2f[p][0], bv, acc0, 0, 0, 0);
        acc1 = __builtin_amdgcn_mfma_f32_16x16x32_bf16(b2f[p][1], bv, acc1, 0, 0, 0);
      }
      if (pos < 70) {
        {
          u16 q0 = f2bf(fmaxf(acc0[0] + c2bv0[0], 0.f));
          u16 q1 = f2bf(fmaxf(acc0[1] + c2bv0[1], 0.f));
          u16 q2 = f2bf(fmaxf(acc0[2] + c2bv0[2], 0.f));
          u16 q3 = f2bf(fmaxf(acc0[3] + c2bv0[3], 0.f));
          u64 pk = (u64)q0 | ((u64)q1 << 16) | ((u64)q2 << 32) | ((u64)q3 << 48);
          u32 wa = (u32)(w*4608 + (pos*32 + grp*4)*2) ^ (u32)((w & 7) << 4);
          *(u64*)((char*)s_c2 + wa) = pk;
        }
        {
          u16 q0 = f2bf(fmaxf(acc1[0] + c2bv1[0], 0.f));
          u16 q1 = f2bf(fmaxf(acc1[1] + c2bv1[1], 0.f));
          u16 q2 = f2bf(fmaxf(acc1[2] + c2bv1[2], 0.f));
          u16 q3 = f2bf(fmaxf(acc1[3] + c2bv1[3], 0.f));
          u64 pk = (u64)q0 | ((u64)q1 << 16) | ((u64)q2 << 32) | ((u64)q3 << 48);
          u32 wa = (u32)(w*4608 + (pos*32 + 16 + grp*4)*2) ^ (u32)((w & 7) << 4);
          *(u64*)((char*)s_c2 + wa) = pk;
        }
      }
    }
    bar_lds();   // (1) s_c2 complete for all samples

    // ==== P2: grid_fc MFMA (4 col-groups x 4 K-quarters) ====
    {
      const u16* bp0 = wsb + WG_OFF + (size_t)((ng*2+0)*16 + arow)*2240 + grp*8;
      const u16* bp1 = wsb + WG_OFF + (size_t)((ng*2+1)*16 + arow)*2240 + grp*8;
      const u32 abase = (u32)(arow*4608 + grp*16);
      const u32 axor  = (u32)((arow & 7) << 4);
      f32x4 ga0 = {0.f,0.f,0.f,0.f}, ga1 = {0.f,0.f,0.f,0.f};
      for (int ks = ksb; ks < kse; ks++) {
        bf16x8 av = *(const bf16x8*)((const char*)s_c2 + ((abase + (u32)ks*64) ^ axor));
        bf16x8 b0 = *(const bf16x8*)(bp0 + (size_t)ks*32);
        bf16x8 b1 = *(const bf16x8*)(bp1 + (size_t)ks*32);
        ga0 = __builtin_amdgcn_mfma_f32_16x16x32_bf16(av, b0, ga0, 0, 0, 0);
        ga1 = __builtin_amdgcn_mfma_f32_16x16x32_bf16(av, b1, ga1, 0, 0, 0);
      }
      #pragma unroll
      for (int r = 0; r < 4; r++) {
        int row = kp*16 + grp*4 + r;
        p_buf[row*132 + (ng*2+0)*16 + arow] = ga0[r];
        p_buf[row*132 + (ng*2+1)*16 + arow] = ga1[r];
      }
    }
    bar_lds();   // (2)

    // ==== P3: reduce 4 K-quarters + bias + relu -> s_tr[0..127] ====
    for (int i = tid; i < 2048; i += 1024) {
      int s = i >> 7, o = i & 127;
      float a = gfbr;
      #pragma unroll
      for (int q = 0; q < 4; q++) a += p_buf[(q*16 + s)*132 + o];
      s_tr[s][o] = f2bf(fmaxf(a, 0.f));
    }
    bar_lds();   // (3)

    // ==== P4: trunk MFMA + direct global store (waves 0-7) | re-zero (8-15) ====
    if (w < 8) {
      f32x4 tacc = {0.f,0.f,0.f,0.f};
      #pragma unroll
      for (int ks = 0; ks < 6; ks++) {
        int k = ks*32 + grp*8;
        bf16x8 av = *(const bf16x8*)&s_tr[arow][k];
        tacc = __builtin_amdgcn_mfma_f32_16x16x32_bf16(av, Btr[ks], tacc, 0, 0, 0);
      }
      int o = w*16 + arow;
      #pragma unroll
      for (int r = 0; r < 4; r++) {
        int s = grp*4 + r;
        trunk_ws[((size_t)(t0 + s)*B_ + bb)*128 + o] = f2bf(fmaxf(tacc[r] + tbvr, 0.f));
      }
    } else {
      // restore zeros over p_buf footprint (act1 halo region)
      for (int j = tid - 512; j < 2112; j += 512) ((uint4*)s_u)[j] = (uint4){0,0,0,0};
    }
    if (haspre) {
      int s = (tid*2)/94, c = (tid*2)%94;
      *(float2*)&s_st[s][c] = npre;
    }
    bar_lds();   // (4) loop end
  }
}

// ---------------------------------------------------------------------------
// K2: MFMA LSTM, 64 blocks x 16 rows x 512 threads. 1 barrier/step (h dbuf).
// Heads removed: h streams to h_ws; K3 computes heads in parallel.
// ---------------------------------------------------------------------------
__global__ __launch_bounds__(512, 1) void k_lstm(
    const u16* __restrict__ trunk_ws, const float* __restrict__ whh,
    const float* __restrict__ wih, const float* __restrict__ bih,
    u16* __restrict__ h_ws)
{
  __shared__ __align__(16) u16 s_tk[2][16*136];
  __shared__ __align__(16) u16 s_h[2][16*136];

  const int tid  = threadIdx.x;
  const int lane = tid & 63;
  const int w    = tid >> 6;        // 0..7
  const int arow = lane & 15;
  const int grp  = lane >> 4;
  const int b0   = blockIdx.x * 16;

  bf16x8 Bv[4][4], Bw[4][4];
  float bihv[4];
  #pragma unroll
  for (int j = 0; j < 4; j++) {
    const int row = j*128 + w*16 + arow;
    bihv[j] = bih[row];
    #pragma unroll
    for (int ks = 0; ks < 4; ks++) {
      const float* s1 = whh + (size_t)row*128 + ks*32 + grp*8;
      const float* s2 = wih + (size_t)row*128 + ks*32 + grp*8;
      float4 a0 = *(const float4*)s1, a1 = *(const float4*)(s1 + 4);
      float4 b0v = *(const float4*)s2, b1v = *(const float4*)(s2 + 4);
      bf16x8 t1, t2;
      t1[0]=(short)f2bf(a0.x); t1[1]=(short)f2bf(a0.y); t1[2]=(short)f2bf(a0.z); t1[3]=(short)f2bf(a0.w);
      t1[4]=(short)f2bf(a1.x); t1[5]=(short)f2bf(a1.y); t1[6]=(short)f2bf(a1.z); t1[7]=(short)f2bf(a1.w);
      t2[0]=(short)f2bf(b0v.x); t2[1]=(short)f2bf(b0v.y); t2[2]=(short)f2bf(b0v.z); t2[3]=(short)f2bf(b0v.w);
      t2[4]=(short)f2bf(b1v.x); t2[5]=(short)f2bf(b1v.y); t2[6]=(short)f2bf(b1v.z); t2[7]=(short)f2bf(b1v.w);
      Bv[j][ks] = t1; Bw[j][ks] = t2;
    }
  }

  for (int i = tid; i < 16*136; i += 512) s_h[0][i] = 0;
  if (tid < 256) {
    int row = tid >> 4, c0 = (tid & 15) * 8;
    *(uint4*)&s_tk[0][row*136 + c0] = *(const uint4*)(trunk_ws + ((size_t)0*B_ + b0 + row)*128 + c0);
    *(uint4*)&s_tk[1][row*136 + c0] = *(const uint4*)(trunk_ws + ((size_t)1*B_ + b0 + row)*128 + c0);
  }
  __syncthreads();

  // xA = X(0)
  f32x4 xA[4];
  #pragma unroll
  for (int j = 0; j < 4; j++) xA[j] = (f32x4){0.f,0.f,0.f,0.f};
  #pragma unroll
  for (int ks = 0; ks < 4; ks++) {
    bf16x8 av = *(const bf16x8*)&s_tk[0][arow*136 + ks*32 + grp*8];
    #pragma unroll
    for (int j = 0; j < 4; j++)
      xA[j] = __builtin_amdgcn_mfma_f32_16x16x32_bf16(av, Bw[j][ks], xA[j], 0, 0, 0);
  }

  float cst[4] = {0.f,0.f,0.f,0.f};

  for (int t = 0; t < T_; t++) {
    const int p = t & 1;
    uint4 pre;
    const bool haspre = (t + 2 < T_) && (tid < 256);
    if (haspre)
      pre = *(const uint4*)(trunk_ws + ((size_t)(t+2)*B_ + b0 + (tid>>4))*128 + (tid&15)*8);

    // phase 1: racc from s_h[p], xB from s_tk[(t+1)&1]
    f32x4 racc[4], xB[4];
    #pragma unroll
    for (int j = 0; j < 4; j++) { racc[j] = (f32x4){0.f,0.f,0.f,0.f}; xB[j] = (f32x4){0.f,0.f,0.f,0.f}; }
    #pragma unroll
    for (int ks = 0; ks < 4; ks++) {
      bf16x8 av = *(const bf16x8*)&s_h[p][arow*136 + ks*32 + grp*8];
      #pragma unroll
      for (int j = 0; j < 4; j++)
        racc[j] = __builtin_amdgcn_mfma_f32_16x16x32_bf16(av, Bv[j][ks], racc[j], 0, 0, 0);
    }
    #pragma unroll
    for (int ks = 0; ks < 4; ks++) {
      bf16x8 av = *(const bf16x8*)&s_tk[(t+1)&1][arow*136 + ks*32 + grp*8];
      #pragma unroll
      for (int j = 0; j < 4; j++)
        xB[j] = __builtin_amdgcn_mfma_f32_16x16x32_bf16(av, Bw[j][ks], xB[j], 0, 0, 0);
    }

    // phase 2 (register-dependent, no barrier): cell + h writes + park
    #pragma unroll
    for (int r = 0; r < 4; r++) {
      float xi = racc[0][r] + xA[0][r] + bihv[0];
      float xf = racc[1][r] + xA[1][r] + bihv[1];
      float xg = racc[2][r] + xA[2][r] + bihv[2];
      float xo = racc[3][r] + xA[3][r] + bihv[3];
      float I = sigm(xi), F = sigm(xf), O = sigm(xo), G = tanh_f(xg);
      cst[r] = F*cst[r] + I*G;
      float hvv = O * tanh_f(cst[r]);
      u16 hb = f2bf(hvv);
      s_h[1-p][(grp*4 + r)*136 + w*16 + arow] = hb;
      h_ws[((size_t)t*B_ + b0 + grp*4 + r)*128 + w*16 + arow] = hb;
    }
    if (haspre)
      *(uint4*)&s_tk[p][(tid>>4)*136 + (tid&15)*8] = pre;
    #pragma unroll
    for (int j = 0; j < 4; j++) xA[j] = xB[j];
    bar_lds();   // h(t) + parked tile visible
  }
}

// ---------------------------------------------------------------------------
// K3: heads. D[wrow][sample] = W5 x h^T via MFMA; grp0 lane holds all 4
// actor logits of its sample; critic via shfl_xor 16. 512 blocks x 256 thr.
// ---------------------------------------------------------------------------
__global__ __launch_bounds__(256, 1) void k_heads(
    const u16* __restrict__ h_ws, const int* __restrict__ actions,
    const float* __restrict__ aw, const float* __restrict__ ab,
    const float* __restrict__ cw, const float* __restrict__ cb,
    float* __restrict__ out)
{
  const int tid  = threadIdx.x;
  const int lane = tid & 63;
  const int w    = tid >> 6;        // 0..3
  const int arow = lane & 15;
  const int grp  = lane >> 4;

  // A-frag: rows 0-3 = actor_w, row 4 = critic_w, rows 5-15 = 0
  bf16x8 Ah[4];
  #pragma unroll
  for (int ks = 0; ks < 4; ks++) {
    bf16x8 v = {0,0,0,0,0,0,0,0};
    if (arow < 4) {
      const float* src = aw + arow*128 + ks*32 + grp*8;
      #pragma unroll
      for (int j = 0; j < 8; j++) v[j] = (short)f2bf(src[j]);
    } else if (arow == 4) {
      const float* src = cw + ks*32 + grp*8;
      #pragma unroll
      for (int j = 0; j < 8; j++) v[j] = (short)f2bf(src[j]);
    }
    Ah[ks] = v;
  }
  const float ab0=ab[0], ab1=ab[1], ab2=ab[2], ab3=ab[3], cb0=cb[0];

  #pragma unroll
  for (int g = 0; g < 4; g++) {
    int m0 = (blockIdx.x*4 + w)*64 + g*16;     // 16 samples, same t
    int t  = m0 >> 10; int bb = m0 & 1023;
    f32x4 acc = {0.f,0.f,0.f,0.f};
    #pragma unroll
    for (int ks = 0; ks < 4; ks++) {
      bf16x8 bv = *(const bf16x8*)(h_ws + ((size_t)t*B_ + bb + arow)*128 + ks*32 + grp*8);
      acc = __builtin_amdgcn_mfma_f32_16x16x32_bf16(Ah[ks], bv, acc, 0, 0, 0);
    }
    float cr = __shfl_xor(acc[0], 16);         // grp0 <- grp1 (row 4 = critic)
    if (grp == 0) {
      float L0 = acc[0] + ab0, L1 = acc[1] + ab1, L2 = acc[2] + ab2, L3 = acc[3] + ab3;
      float Lv = cr + cb0;
      float mm = fmaxf(fmaxf(L0, L1), fmaxf(L2, L3));
      float e0 = __expf(L0-mm), e1 = __expf(L1-mm), e2 = __expf(L2-mm), e3 = __expf(L3-mm);
      float S = e0+e1+e2+e3; float lse = __logf(S);
      float p0=L0-mm-lse, p1=L1-mm-lse, p2=L2-mm-lse, p3=L3-mm-lse;
      int n = (bb + arow)*T_ + t;
      int a = actions[n];
      float lpa = (a==0)?p0:(a==1)?p1:(a==2)?p2:p3;
      float ent = -(e0*p0 + e1*p1 + e2*p2 + e3*p3) / S;
      out[n] = lpa; out[NBT + n] = Lv; out[2*NBT + n] = ent;
    }
  }
}

extern "C" void kernel_launch(void* const* d_in, const int* in_sizes, int n_in,
                              void* d_out, int out_size, void* d_ws, size_t ws_size,
                              hipStream_t stream) {
  const float* states = (const float*)d_in[0];
  const int*   actions= (const int*)  d_in[1];
  const float* c1w = (const float*)d_in[2];
  const float* c1b = (const float*)d_in[3];
  const float* c2w = (const float*)d_in[4];
  const float* c2b = (const float*)d_in[5];
  const float* gfw = (const float*)d_in[6];
  const float* gfb = (const float*)d_in[7];
  const float* cfw = (const float*)d_in[8];
  const float* cfb = (const float*)d_in[9];
  const float* tw  = (const float*)d_in[10];
  const float* tbv = (const float*)d_in[11];
  const float* wih = (const float*)d_in[12];
  const float* bih = (const float*)d_in[13];
  const float* whh = (const float*)d_in[14];
  const float* aw  = (const float*)d_in[15];
  const float* ab  = (const float*)d_in[16];
  const float* cw  = (const float*)d_in[17];
  const float* cb  = (const float*)d_in[18];
  float* out = (float*)d_out;

  u16* wsb   = (u16*)d_ws;
  u16* trunk = (u16*)((char*)d_ws + TRUNK_BYTE_OFF);
  u16* h_ws  = (u16*)((char*)d_ws + H_BYTE_OFF);

  k_cvt<<<(CVT_TOTAL + 255)/256, 256, 0, stream>>>(gfw, tw, wih, c2w, c1w, wsb);
  k_features<<<FBLK, 1024, 0, stream>>>(states, c1b, c2b, gfb,
                                        cfw, cfb, tbv, wsb, trunk);
  k_lstm<<<B_/16, 512, 0, stream>>>(trunk, whh, wih, bih, h_ws);
  k_heads<<<512, 256, 0, stream>>>(h_ws, actions, aw, ab, cw, cb, out);
}

// Round 9
// 1178.283 us; speedup vs baseline: 1.7488x; 1.0498x over previous
//
#include <hip/hip_runtime.h>
#include <hip/hip_bf16.h>

typedef unsigned int  u32;
typedef unsigned short u16;
typedef unsigned long long u64;
typedef __attribute__((ext_vector_type(8))) short bf16x8;
typedef __attribute__((ext_vector_type(4))) float f32x4;

#define B_   1024
#define T_   128
#define NBT  (B_*T_)
#define CHUNK 32768
#define NCHUNK 4

// ---- wsb (u16 element offsets) ----
#define WG_OFF   0          // grid_fc [128][2240] bf16, K permuted: k' = pos*32 + ch
#define WT_OFF   286720     // trunk   [128][192]  bf16
#define WIH_OFF  311296     // (unused; layout stability)
#define W2_OFF   376832     // conv2   [32][160]   bf16 (tap-pair, tap9=0)
#define W1C_OFF  381952     // conv1   [16][32]    bf16 (taps 0-8 + zeros)
#define CVT_TOTAL 382464

// ---- d_ws byte offsets (ws_size proven in [256MiB,257MiB)) ----
#define TRUNK_OFF (1ull<<20)      // [T][B][128] bf16 = 33.55 MB
#define H_OFF     (36ull<<20)     // [T][B][128] bf16 = 33.55 MB
#define CTX_OFF   (72ull<<20)     // [BT][64]    bf16 = 16.78 MB
#define C2_OFF    (92ull<<20)     // chunk [32768][2240] bf16 = 146.8 MB -> ends 232 MiB

__device__ __forceinline__ u16 f2bf(float f){
  u32 u = __float_as_uint(f);
  u32 r = u + 0x7fffu + ((u >> 16) & 1u);   // RNE
  return (u16)(r >> 16);
}
__device__ __forceinline__ float bf2f(u16 u){ return __uint_as_float((u32)u << 16); }
__device__ __forceinline__ float sigm(float x){ return 1.f / (1.f + __expf(-x)); }
__device__ __forceinline__ float tanh_f(float x){ return 2.f / (1.f + __expf(-2.f*x)) - 1.f; }

// LDS-only barrier: waits ds ops, leaves global loads/stores in flight.
__device__ __forceinline__ void bar_lds() {
  __builtin_amdgcn_sched_barrier(0);
  asm volatile("s_waitcnt lgkmcnt(0)" ::: "memory");
  __builtin_amdgcn_s_barrier();
  __builtin_amdgcn_sched_barrier(0);
}

// ---------------------------------------------------------------------------
// K0: weights -> bf16 workspace (unchanged, verified).
// ---------------------------------------------------------------------------
__global__ void k_cvt(const float* __restrict__ gfw, const float* __restrict__ tw,
                      const float* __restrict__ wih, const float* __restrict__ c2w,
                      const float* __restrict__ c1w, u16* __restrict__ wsb) {
  int i = blockIdx.x * 256 + threadIdx.x;
  if (i >= CVT_TOTAL) return;
  float v;
  if (i < WT_OFF) {
    int o = i / 2240; int k = i - o*2240;
    int pos = k >> 5, ch = k & 31;
    v = gfw[o*2240 + ch*70 + pos];
  }
  else if (i < WIH_OFF)  v = tw[i - WT_OFF];
  else if (i < W2_OFF)   v = wih[i - WIH_OFF];
  else if (i < W1C_OFF) {
    int j = i - W2_OFF; int co = j / 160; int k = j - co*160;
    int tap = k >> 4; int ci = k & 15;
    v = (tap < 9) ? c2w[co*144 + ci*9 + tap] : 0.f;
  } else {
    int j = i - W1C_OFF; int ch = j >> 5; int k = j & 31;
    v = (k < 9) ? c1w[ch*9 + k] : 0.f;
  }
  wsb[i] = f2bf(v);
}

// ---------------------------------------------------------------------------
// K1a: conv1 + conv2 + ctx_fc. 8 samples/block, 512 threads (8 waves),
// 37 KB LDS -> multi-block/CU. conv1 B-frag gathered straight from s_st
// (no im2col buffer). conv2 stores c2 [n][k'=pos*32+ch] directly to global.
// ---------------------------------------------------------------------------
__global__ __launch_bounds__(512, 4) void k_conv(
    const float* __restrict__ states,   // chunk base
    const float* __restrict__ c1b, const float* __restrict__ c2b,
    const float* __restrict__ cfw, const float* __restrict__ cfb,
    const u16* __restrict__ wsb,
    u16* __restrict__ c2g,              // chunk [32768][2240]
    u16* __restrict__ ctxg)             // chunk [32768][64]
{
  __shared__ float s_st[8][96];                   // 3 KB
  __shared__ __align__(16) u16 act1[8*108*16];    // 27.6 KB, swizzled
  __shared__ float s_cf[64][25];                  // 6.4 KB

  const int tid  = threadIdx.x;
  const int lane = tid & 63;
  const int w    = tid >> 6;        // 0..7
  const int arow = lane & 15;
  const int grp  = lane >> 4;
  const int m0   = blockIdx.x * 8;  // chunk-local sample base

  // persistent frags
  bf16x8 Bc1 = *(const bf16x8*)(wsb + W1C_OFF + arow*32 + grp*8);
  bf16x8 b2f[5][2];
  #pragma unroll
  for (int p = 0; p < 5; p++)
    #pragma unroll
    for (int nt = 0; nt < 2; nt++)
      b2f[p][nt] = *(const bf16x8*)(wsb + W2_OFF + (nt*16 + arow)*160 + p*32 + grp*8);
  float c1bv[4], c2bv0[4], c2bv1[4];
  #pragma unroll
  for (int r = 0; r < 4; r++) {
    c1bv[r]  = c1b[grp*4 + r];
    c2bv0[r] = c2b[grp*4 + r];
    c2bv1[r] = c2b[16 + grp*4 + r];
  }
  const float cfbr = cfb[lane];

  // ---- stage ----
  if (tid < 376) {
    float2 v = *(const float2*)(states + (size_t)m0*94 + tid*2);
    int s = (tid*2)/94, c = (tid*2)%94;
    *(float2*)&s_st[s][c] = v;
  }
  for (int i = tid; i < 1728; i += 512) ((uint4*)act1)[i] = (uint4){0,0,0,0};
  for (int i = tid; i < 1536; i += 512) s_cf[i/24][i%24] = cfw[i];
  __syncthreads();

  const bf16x8 zv = {0,0,0,0,0,0,0,0};

  // ---- conv1 MFMA: 35 tiles (8 samples x 70 pos), B-frag direct gather ----
  for (int mt = w; mt < 35; mt += 8) {
    int row = mt*16 + arow;
    int s = (int)(((u32)row * 59919u) >> 22); int pos = row - s*70;
    int y = (int)(((u32)pos * 6554u) >> 16);  int x = pos - y*10;
    bf16x8 pf = zv;
    if (grp == 0) {
      const float* gs = &s_st[s][0];
      #pragma unroll
      for (int t = 0; t < 8; t++) {
        int dy = t/3, dx = t - (t/3)*3;
        int yy = y + dy - 1, xx = x + dx - 1;
        bool ok = (yy >= 0) & (yy < 7) & (xx >= 0) & (xx < 10);
        float v = gs[ok ? yy*10 + xx : 0];
        pf[t] = (short)f2bf(ok ? v : 0.f);
      }
    } else if (grp == 1) {
      int yy = y + 1, xx = x + 1;     // tap 8: dy=2,dx=2
      bool ok = (yy < 7) & (xx < 10);
      float v = s_st[s][ok ? yy*10 + xx : 0];
      pf[0] = (short)f2bf(ok ? v : 0.f);
    }
    f32x4 acc = __builtin_amdgcn_mfma_f32_16x16x32_bf16(Bc1, pf, (f32x4){0.f,0.f,0.f,0.f}, 0, 0, 0);
    int hp = (y+1)*12 + (x+1);
    u16 q0 = f2bf(fmaxf(acc[0] + c1bv[0], 0.f));
    u16 q1 = f2bf(fmaxf(acc[1] + c1bv[1], 0.f));
    u16 q2 = f2bf(fmaxf(acc[2] + c1bv[2], 0.f));
    u16 q3 = f2bf(fmaxf(acc[3] + c1bv[3], 0.f));
    u64 pk = (u64)q0 | ((u64)q1 << 16) | ((u64)q2 << 32) | ((u64)q3 << 48);
    u32 wa = (u32)(((s*108 + hp)*16 + grp*4)*2) ^ (u32)((hp & 7) << 4);
    *(u64*)((char*)act1 + wa) = pk;
  }
  __syncthreads();

  // ---- conv2 MFMA (swapped operands), direct global u64 stores ----
  for (int mt = w; mt < 35; mt += 8) {
    int row = mt*16 + arow;
    int s = (int)(((u32)row * 59919u) >> 22); int pos = row - s*70;
    int y = (int)(((u32)pos * 6554u) >> 16);  int x = pos - y*10;
    f32x4 acc0 = {0.f,0.f,0.f,0.f}, acc1 = {0.f,0.f,0.f,0.f};
    #pragma unroll
    for (int p = 0; p < 5; p++) {
      int tap = p*2 + (grp >> 1); if (tap > 8) tap = 8;
      int dy = (tap * 11) >> 5; int dx = tap - dy*3;
      int hp = (y + dy)*12 + (x + dx);
      u32 ra = (u32)(((s*108 + hp)*16 + (grp & 1)*8)*2) ^ (u32)((hp & 7) << 4);
      bf16x8 bv = *(const bf16x8*)((const char*)act1 + ra);
      acc0 = __builtin_amdgcn_mfma_f32_16x16x32_bf16(b2f[p][0], bv, acc0, 0, 0, 0);
      acc1 = __builtin_amdgcn_mfma_f32_16x16x32_bf16(b2f[p][1], bv, acc1, 0, 0, 0);
    }
    {
      u16 q0 = f2bf(fmaxf(acc0[0] + c2bv0[0], 0.f));
      u16 q1 = f2bf(fmaxf(acc0[1] + c2bv0[1], 0.f));
      u16 q2 = f2bf(fmaxf(acc0[2] + c2bv0[2], 0.f));
      u16 q3 = f2bf(fmaxf(acc0[3] + c2bv0[3], 0.f));
      u64 pk = (u64)q0 | ((u64)q1 << 16) | ((u64)q2 << 32) | ((u64)q3 << 48);
      *(u64*)(c2g + (size_t)(m0 + s)*2240 + pos*32 + grp*4) = pk;
    }
    {
      u16 q0 = f2bf(fmaxf(acc1[0] + c2bv1[0], 0.f));
      u16 q1 = f2bf(fmaxf(acc1[1] + c2bv1[1], 0.f));
      u16 q2 = f2bf(fmaxf(acc1[2] + c2bv1[2], 0.f));
      u16 q3 = f2bf(fmaxf(acc1[3] + c2bv1[3], 0.f));
      u64 pk = (u64)q0 | ((u64)q1 << 16) | ((u64)q2 << 32) | ((u64)q3 << 48);
      *(u64*)(c2g + (size_t)(m0 + s)*2240 + pos*32 + 16 + grp*4) = pk;
    }
  }

  // ---- ctx_fc: sample w, out lane ----
  {
    float a = cfbr;
    #pragma unroll
    for (int k = 0; k < 24; k++) a = fmaf(s_cf[lane][k], s_st[w][70 + k], a);
    ctxg[(size_t)(m0 + w)*64 + lane] = f2bf(fmaxf(a, 0.f));
  }
}

// ---------------------------------------------------------------------------
// K1b: grid_fc + ctx concat + trunk as a 128-sample-tile GEMM.
// A (c2) direct-global per wave, 2-deep prefetch; B (Wg) LDS double-buffered
// with 36-u16 padded rows (conflict-free b128 reads); lgkm-only barriers.
// ---------------------------------------------------------------------------
__global__ __launch_bounds__(512, 4) void k_gemm(
    const u16* __restrict__ c2g, const u16* __restrict__ ctxg,
    const float* __restrict__ gfb, const float* __restrict__ tbv,
    const u16* __restrict__ wsb, u16* __restrict__ trunk_ws, int nbase)
{
  __shared__ __align__(16) u16 s_b[2][128*36];   // 18.4 KB
  __shared__ __align__(16) u16 s_g[128*204];     // 52.2 KB

  const int tid  = threadIdx.x;
  const int lane = tid & 63;
  const int w    = tid >> 6;        // 0..7 = m-sub-tile
  const int arow = lane & 15;
  const int grp  = lane >> 4;
  const int m0   = blockIdx.x * 128;

  float gfbv[8], tbvv[8];
  #pragma unroll
  for (int nt = 0; nt < 8; nt++) {
    gfbv[nt] = gfb[nt*16 + arow];
    tbvv[nt] = tbv[nt*16 + arow];
  }

  const int srow = tid >> 2, sseg = (tid & 3) * 8;
  const u16* wg = wsb + WG_OFF;
  const u16* ap = c2g + (size_t)(m0 + w*16 + arow) * 2240 + grp*8;

  // prologue: stage B(0), prefetch A(0),A(1)
  {
    uint4 b0 = *(const uint4*)(wg + (size_t)srow*2240 + sseg);
    *(uint4*)&s_b[0][srow*36 + sseg] = b0;
  }
  bf16x8 a_cur = *(const bf16x8*)(ap);
  bf16x8 a_nxt = *(const bf16x8*)(ap + 32);
  f32x4 acc[8];
  #pragma unroll
  for (int nt = 0; nt < 8; nt++) acc[nt] = (f32x4){0.f,0.f,0.f,0.f};
  __syncthreads();

  #pragma unroll 2
  for (int ks = 0; ks < 70; ks++) {
    uint4 bnew;
    if (ks < 69)
      bnew = *(const uint4*)(wg + (size_t)srow*2240 + (ks+1)*32 + sseg);
    bf16x8 a_fut = a_nxt;
    if (ks < 68)
      a_fut = *(const bf16x8*)(ap + (size_t)(ks+2)*32);
    const u16* sb = &s_b[ks & 1][0];
    #pragma unroll
    for (int nt = 0; nt < 8; nt++) {
      bf16x8 bv = *(const bf16x8*)&sb[(nt*16 + arow)*36 + grp*8];
      acc[nt] = __builtin_amdgcn_mfma_f32_16x16x32_bf16(a_cur, bv, acc[nt], 0, 0, 0);
    }
    if (ks < 69)
      *(uint4*)&s_b[(ks+1) & 1][srow*36 + sseg] = bnew;
    a_cur = a_nxt; a_nxt = a_fut;
    bar_lds();
  }

  // g -> s_g cols 0..127 (+bias, relu)
  #pragma unroll
  for (int nt = 0; nt < 8; nt++)
    #pragma unroll
    for (int r = 0; r < 4; r++)
      s_g[(w*16 + grp*4 + r)*204 + nt*16 + arow] = f2bf(fmaxf(acc[nt][r] + gfbv[nt], 0.f));

  // ctx -> s_g cols 128..191
  {
    int row = tid >> 2, seg = (tid & 3) * 16;
    uint4 c0 = *(const uint4*)(ctxg + (size_t)(m0 + row)*64 + seg);
    uint4 c1 = *(const uint4*)(ctxg + (size_t)(m0 + row)*64 + seg + 8);
    *(uint4*)&s_g[row*204 + 128 + seg]     = c0;
    *(uint4*)&s_g[row*204 + 128 + seg + 8] = c1;
  }
  bar_lds();

  // trunk: K=192; B from global (L2-hot); write back into s_g cols 0..127
  {
    f32x4 tacc[8];
    #pragma unroll
    for (int nt = 0; nt < 8; nt++) tacc[nt] = (f32x4){0.f,0.f,0.f,0.f};
    #pragma unroll
    for (int ks = 0; ks < 6; ks++) {
      bf16x8 av = *(const bf16x8*)&s_g[(w*16 + arow)*204 + ks*32 + grp*8];
      #pragma unroll
      for (int nt = 0; nt < 8; nt++) {
        bf16x8 bv = *(const bf16x8*)(wsb + WT_OFF + (size_t)(nt*16 + arow)*192 + ks*32 + grp*8);
        tacc[nt] = __builtin_amdgcn_mfma_f32_16x16x32_bf16(av, bv, tacc[nt], 0, 0, 0);
      }
    }
    // per-wave in-order LDS: these writes to own rows follow own reads
    #pragma unroll
    for (int nt = 0; nt < 8; nt++)
      #pragma unroll
      for (int r = 0; r < 4; r++)
        s_g[(w*16 + grp*4 + r)*204 + nt*16 + arow] = f2bf(fmaxf(tacc[nt][r] + tbvv[nt], 0.f));
  }
  bar_lds();

  // store trunk tile: sample n = nbase+m0+row -> t=row, b=(nbase+m0)>>7
  {
    const int bb = (nbase + m0) >> 7;
    int row = tid >> 2, seg = (tid & 3) * 32;
    #pragma unroll
    for (int j = 0; j < 4; j++) {
      uint4 v = *(const uint4*)&s_g[row*204 + seg + j*8];
      *(uint4*)(trunk_ws + ((size_t)row*B_ + bb)*128 + seg + j*8) = v;
    }
  }
}

// ---------------------------------------------------------------------------
// K2: MFMA LSTM (verbatim R8 — known good).
// ---------------------------------------------------------------------------
__global__ __launch_bounds__(512, 1) void k_lstm(
    const u16* __restrict__ trunk_ws, const float* __restrict__ whh,
    const float* __restrict__ wih, const float* __restrict__ bih,
    u16* __restrict__ h_ws)
{
  __shared__ __align__(16) u16 s_tk[2][16*136];
  __shared__ __align__(16) u16 s_h[2][16*136];

  const int tid  = threadIdx.x;
  const int lane = tid & 63;
  const int w    = tid >> 6;
  const int arow = lane & 15;
  const int grp  = lane >> 4;
  const int b0   = blockIdx.x * 16;

  bf16x8 Bv[4][4], Bw[4][4];
  float bihv[4];
  #pragma unroll
  for (int j = 0; j < 4; j++) {
    const int row = j*128 + w*16 + arow;
    bihv[j] = bih[row];
    #pragma unroll
    for (int ks = 0; ks < 4; ks++) {
      const float* s1 = whh + (size_t)row*128 + ks*32 + grp*8;
      const float* s2 = wih + (size_t)row*128 + ks*32 + grp*8;
      float4 a0 = *(const float4*)s1, a1 = *(const float4*)(s1 + 4);
      float4 b0v = *(const float4*)s2, b1v = *(const float4*)(s2 + 4);
      bf16x8 t1, t2;
      t1[0]=(short)f2bf(a0.x); t1[1]=(short)f2bf(a0.y); t1[2]=(short)f2bf(a0.z); t1[3]=(short)f2bf(a0.w);
      t1[4]=(short)f2bf(a1.x); t1[5]=(short)f2bf(a1.y); t1[6]=(short)f2bf(a1.z); t1[7]=(short)f2bf(a1.w);
      t2[0]=(short)f2bf(b0v.x); t2[1]=(short)f2bf(b0v.y); t2[2]=(short)f2bf(b0v.z); t2[3]=(short)f2bf(b0v.w);
      t2[4]=(short)f2bf(b1v.x); t2[5]=(short)f2bf(b1v.y); t2[6]=(short)f2bf(b1v.z); t2[7]=(short)f2bf(b1v.w);
      Bv[j][ks] = t1; Bw[j][ks] = t2;
    }
  }

  for (int i = tid; i < 16*136; i += 512) s_h[0][i] = 0;
  if (tid < 256) {
    int row = tid >> 4, c0 = (tid & 15) * 8;
    *(uint4*)&s_tk[0][row*136 + c0] = *(const uint4*)(trunk_ws + ((size_t)0*B_ + b0 + row)*128 + c0);
    *(uint4*)&s_tk[1][row*136 + c0] = *(const uint4*)(trunk_ws + ((size_t)1*B_ + b0 + row)*128 + c0);
  }
  __syncthreads();

  f32x4 xA[4];
  #pragma unroll
  for (int j = 0; j < 4; j++) xA[j] = (f32x4){0.f,0.f,0.f,0.f};
  #pragma unroll
  for (int ks = 0; ks < 4; ks++) {
    bf16x8 av = *(const bf16x8*)&s_tk[0][arow*136 + ks*32 + grp*8];
    #pragma unroll
    for (int j = 0; j < 4; j++)
      xA[j] = __builtin_amdgcn_mfma_f32_16x16x32_bf16(av, Bw[j][ks], xA[j], 0, 0, 0);
  }

  float cst[4] = {0.f,0.f,0.f,0.f};

  for (int t = 0; t < T_; t++) {
    const int p = t & 1;
    uint4 pre;
    const bool haspre = (t + 2 < T_) && (tid < 256);
    if (haspre)
      pre = *(const uint4*)(trunk_ws + ((size_t)(t+2)*B_ + b0 + (tid>>4))*128 + (tid&15)*8);

    f32x4 racc[4], xB[4];
    #pragma unroll
    for (int j = 0; j < 4; j++) { racc[j] = (f32x4){0.f,0.f,0.f,0.f}; xB[j] = (f32x4){0.f,0.f,0.f,0.f}; }
    #pragma unroll
    for (int ks = 0; ks < 4; ks++) {
      bf16x8 av = *(const bf16x8*)&s_h[p][arow*136 + ks*32 + grp*8];
      #pragma unroll
      for (int j = 0; j < 4; j++)
        racc[j] = __builtin_amdgcn_mfma_f32_16x16x32_bf16(av, Bv[j][ks], racc[j], 0, 0, 0);
    }
    #pragma unroll
    for (int ks = 0; ks < 4; ks++) {
      bf16x8 av = *(const bf16x8*)&s_tk[(t+1)&1][arow*136 + ks*32 + grp*8];
      #pragma unroll
      for (int j = 0; j < 4; j++)
        xB[j] = __builtin_amdgcn_mfma_f32_16x16x32_bf16(av, Bw[j][ks], xB[j], 0, 0, 0);
    }

    #pragma unroll
    for (int r = 0; r < 4; r++) {
      float xi = racc[0][r] + xA[0][r] + bihv[0];
      float xf = racc[1][r] + xA[1][r] + bihv[1];
      float xg = racc[2][r] + xA[2][r] + bihv[2];
      float xo = racc[3][r] + xA[3][r] + bihv[3];
      float I = sigm(xi), F = sigm(xf), O = sigm(xo), G = tanh_f(xg);
      cst[r] = F*cst[r] + I*G;
      float hvv = O * tanh_f(cst[r]);
      u16 hb = f2bf(hvv);
      s_h[1-p][(grp*4 + r)*136 + w*16 + arow] = hb;
      h_ws[((size_t)t*B_ + b0 + grp*4 + r)*128 + w*16 + arow] = hb;
    }
    if (haspre)
      *(uint4*)&s_tk[p][(tid>>4)*136 + (tid&15)*8] = pre;
    #pragma unroll
    for (int j = 0; j < 4; j++) xA[j] = xB[j];
    bar_lds();
  }
}

// ---------------------------------------------------------------------------
// K3: heads (verbatim R8 — known good).
// ---------------------------------------------------------------------------
__global__ __launch_bounds__(256, 1) void k_heads(
    const u16* __restrict__ h_ws, const int* __restrict__ actions,
    const float* __restrict__ aw, const float* __restrict__ ab,
    const float* __restrict__ cw, const float* __restrict__ cb,
    float* __restrict__ out)
{
  const int tid  = threadIdx.x;
  const int lane = tid & 63;
  const int w    = tid >> 6;
  const int arow = lane & 15;
  const int grp  = lane >> 4;

  bf16x8 Ah[4];
  #pragma unroll
  for (int ks = 0; ks < 4; ks++) {
    bf16x8 v = {0,0,0,0,0,0,0,0};
    if (arow < 4) {
      const float* src = aw + arow*128 + ks*32 + grp*8;
      #pragma unroll
      for (int j = 0; j < 8; j++) v[j] = (short)f2bf(src[j]);
    } else if (arow == 4) {
      const float* src = cw + ks*32 + grp*8;
      #pragma unroll
      for (int j = 0; j < 8; j++) v[j] = (short)f2bf(src[j]);
    }
    Ah[ks] = v;
  }
  const float ab0=ab[0], ab1=ab[1], ab2=ab[2], ab3=ab[3], cb0=cb[0];

  #pragma unroll
  for (int g = 0; g < 4; g++) {
    int m0 = (blockIdx.x*4 + w)*64 + g*16;
    int t  = m0 >> 10; int bb = m0 & 1023;
    f32x4 acc = {0.f,0.f,0.f,0.f};
    #pragma unroll
    for (int ks = 0; ks < 4; ks++) {
      bf16x8 bv = *(const bf16x8*)(h_ws + ((size_t)t*B_ + bb + arow)*128 + ks*32 + grp*8);
      acc = __builtin_amdgcn_mfma_f32_16x16x32_bf16(Ah[ks], bv, acc, 0, 0, 0);
    }
    float cr = __shfl_xor(acc[0], 16);
    if (grp == 0) {
      float L0 = acc[0] + ab0, L1 = acc[1] + ab1, L2 = acc[2] + ab2, L3 = acc[3] + ab3;
      float Lv = cr + cb0;
      float mm = fmaxf(fmaxf(L0, L1), fmaxf(L2, L3));
      float e0 = __expf(L0-mm), e1 = __expf(L1-mm), e2 = __expf(L2-mm), e3 = __expf(L3-mm);
      float S = e0+e1+e2+e3; float lse = __logf(S);
      float p0=L0-mm-lse, p1=L1-mm-lse, p2=L2-mm-lse, p3=L3-mm-lse;
      int n = (bb + arow)*T_ + t;
      int a = actions[n];
      float lpa = (a==0)?p0:(a==1)?p1:(a==2)?p2:p3;
      float ent = -(e0*p0 + e1*p1 + e2*p2 + e3*p3) / S;
      out[n] = lpa; out[NBT + n] = Lv; out[2*NBT + n] = ent;
    }
  }
}

extern "C" void kernel_launch(void* const* d_in, const int* in_sizes, int n_in,
                              void* d_out, int out_size, void* d_ws, size_t ws_size,
                              hipStream_t stream) {
  const float* states = (const float*)d_in[0];
  const int*   actions= (const int*)  d_in[1];
  const float* c1w = (const float*)d_in[2];
  const float* c1b = (const float*)d_in[3];
  const float* c2w = (const float*)d_in[4];
  const float* c2b = (const float*)d_in[5];
  const float* gfw = (const float*)d_in[6];
  const float* gfb = (const float*)d_in[7];
  const float* cfw = (const float*)d_in[8];
  const float* cfb = (const float*)d_in[9];
  const float* tw  = (const float*)d_in[10];
  const float* tbv = (const float*)d_in[11];
  const float* wih = (const float*)d_in[12];
  const float* bih = (const float*)d_in[13];
  const float* whh = (const float*)d_in[14];
  const float* aw  = (const float*)d_in[15];
  const float* ab  = (const float*)d_in[16];
  const float* cw  = (const float*)d_in[17];
  const float* cb  = (const float*)d_in[18];
  float* out = (float*)d_out;

  u16* wsb   = (u16*)d_ws;
  u16* trunk = (u16*)((char*)d_ws + TRUNK_OFF);
  u16* h_ws  = (u16*)((char*)d_ws + H_OFF);
  u16* ctxg  = (u16*)((char*)d_ws + CTX_OFF);
  u16* c2g   = (u16*)((char*)d_ws + C2_OFF);

  k_cvt<<<(CVT_TOTAL + 255)/256, 256, 0, stream>>>(gfw, tw, wih, c2w, c1w, wsb);

  for (int c = 0; c < NCHUNK; c++) {
    const float* st_c = states + (size_t)c * CHUNK * 94;
    u16* ctx_c = ctxg + (size_t)c * CHUNK * 64;
    k_conv<<<CHUNK/8, 512, 0, stream>>>(st_c, c1b, c2b, cfw, cfb, wsb, c2g, ctx_c);
    k_gemm<<<CHUNK/128, 512, 0, stream>>>(c2g, ctx_c, gfb, tbv, wsb, trunk, c*CHUNK);
  }
  k_lstm<<<B_/16, 512, 0, stream>>>(trunk, whh, wih, bih, h_ws);
  k_heads<<<512, 256, 0, stream>>>(h_ws, actions, aw, ab, cw, cb, out);
}